// Round 1
// baseline (18528.830 us; speedup 1.0000x reference)
//
#include <hip/hip_runtime.h>
#include <math.h>

#define D_ 1024
#define C_ 512
#define H_ 16
#define DH_ 64
#define P_ 16
#define FF_ 4096
#define S_ 4096
#define B_ 4
#define NC_ 8

// ---------------------------------------------------------------- utilities
__device__ __forceinline__ float sigmoidf_(float x) { return 1.0f / (1.0f + expf(-x)); }

// ---------------------------------------------------------------- LayerNorm
// One block per row (D=1024, 256 threads x 4 elems). Optionally adds `add`
// (flat row-major) to the batch-mapped source before normalizing.
__global__ __launch_bounds__(256) void ln_kernel(
    const float* __restrict__ x, long long xBatchStride, int rowsPerBatch,
    const float* __restrict__ add,
    const float* __restrict__ g, const float* __restrict__ beta,
    float* __restrict__ out)
{
    __shared__ float sbuf[4];
    int row = blockIdx.x;
    int bb = row / rowsPerBatch, s = row - bb * rowsPerBatch;
    const float* xr = x + (long long)bb * xBatchStride + (long long)s * D_;
    int t = threadIdx.x;
    float v[4];
    float4 xv = *(const float4*)(xr + t * 4);
    v[0] = xv.x; v[1] = xv.y; v[2] = xv.z; v[3] = xv.w;
    if (add) {
        float4 av = *(const float4*)(add + (long long)row * D_ + t * 4);
        v[0] += av.x; v[1] += av.y; v[2] += av.z; v[3] += av.w;
    }
    float ls = v[0] + v[1] + v[2] + v[3];
    #pragma unroll
    for (int off = 32; off >= 1; off >>= 1) ls += __shfl_down(ls, off, 64);
    if ((t & 63) == 0) sbuf[t >> 6] = ls;
    __syncthreads();
    float mean = (sbuf[0] + sbuf[1] + sbuf[2] + sbuf[3]) * (1.0f / D_);
    __syncthreads();
    float lv = 0.f;
    #pragma unroll
    for (int i = 0; i < 4; i++) { float d = v[i] - mean; lv += d * d; }
    #pragma unroll
    for (int off = 32; off >= 1; off >>= 1) lv += __shfl_down(lv, off, 64);
    if ((t & 63) == 0) sbuf[t >> 6] = lv;
    __syncthreads();
    float var = (sbuf[0] + sbuf[1] + sbuf[2] + sbuf[3]) * (1.0f / D_);
    float r = rsqrtf(var + 1e-5f);
    float* orow = out + (long long)row * D_;
    #pragma unroll
    for (int i = 0; i < 4; i++) {
        int c = t * 4 + i;
        orow[c] = (v[i] - mean) * r * g[c] + beta[c];
    }
}

// ---------------------------------------------------------------- row L2-normalize (km)
__global__ __launch_bounds__(256) void rownorm_kernel(float* __restrict__ a)
{
    __shared__ float sbuf[4];
    int row = blockIdx.x;
    int t = threadIdx.x;
    float* ar = a + (long long)row * D_;
    float4 xv = *(const float4*)(ar + t * 4);
    float ls = xv.x * xv.x + xv.y * xv.y + xv.z * xv.z + xv.w * xv.w;
    #pragma unroll
    for (int off = 32; off >= 1; off >>= 1) ls += __shfl_down(ls, off, 64);
    if ((t & 63) == 0) sbuf[t >> 6] = ls;
    __syncthreads();
    float ss = sbuf[0] + sbuf[1] + sbuf[2] + sbuf[3];
    float sc = rsqrtf(ss + 1e-6f);
    xv.x *= sc; xv.y *= sc; xv.z *= sc; xv.w *= sc;
    *(float4*)(ar + t * 4) = xv;
}

// ---------------------------------------------------------------- generic fp32 GEMM
// out[b*outBatchStride + s*N + col] = A[row,:] @ Bw(+batch) [+bias] [+resid]
// A: flat Mrows x K. Bw: K x N (bBatchStride selects per-batch matrix, 0 = shared).
// All dims multiples of tile sizes (no guards): M%64==0, N%64==0, K%16==0.
__global__ __launch_bounds__(256) void gemm_kernel(
    const float* __restrict__ A, const float* __restrict__ Bw,
    const float* __restrict__ bias, const float* __restrict__ resid,
    float* __restrict__ out,
    int K, int N,
    long long bBatchStride, int rowsPerBatch, long long outBatchStride)
{
    __shared__ float As[16][64];
    __shared__ float Bs[16][64];
    int col0 = blockIdx.x * 64;
    int row0 = blockIdx.y * 64;
    const float* Bp = Bw + (bBatchStride ? (long long)(row0 / rowsPerBatch) * bBatchStride : 0);
    int t = threadIdx.x;
    int tx = t & 15, ty = t >> 4;
    float acc[4][4] = {};
    for (int k0 = 0; k0 < K; k0 += 16) {
        {
            int m = t >> 2;
            int kg = (t & 3) * 4;
            float4 av = *(const float4*)(A + (long long)(row0 + m) * K + k0 + kg);
            As[kg + 0][m] = av.x; As[kg + 1][m] = av.y;
            As[kg + 2][m] = av.z; As[kg + 3][m] = av.w;
        }
        {
            int kk = t >> 4;
            int n4 = (t & 15) * 4;
            float4 bv = *(const float4*)(Bp + (long long)(k0 + kk) * N + col0 + n4);
            *(float4*)&Bs[kk][n4] = bv;
        }
        __syncthreads();
        #pragma unroll
        for (int kk = 0; kk < 16; kk++) {
            float a[4], b4[4];
            #pragma unroll
            for (int i = 0; i < 4; i++) a[i] = As[kk][ty * 4 + i];
            #pragma unroll
            for (int j = 0; j < 4; j++) b4[j] = Bs[kk][tx * 4 + j];
            #pragma unroll
            for (int i = 0; i < 4; i++)
                #pragma unroll
                for (int j = 0; j < 4; j++) acc[i][j] += a[i] * b4[j];
        }
        __syncthreads();
    }
    #pragma unroll
    for (int i = 0; i < 4; i++) {
        int row = row0 + ty * 4 + i;
        int bb = row / rowsPerBatch, s = row - bb * rowsPerBatch;
        float* orow = out + (long long)bb * outBatchStride + (long long)s * N + col0 + tx * 4;
        const float* rrow = resid ? resid + (long long)row * N + col0 + tx * 4 : nullptr;
        #pragma unroll
        for (int j = 0; j < 4; j++) {
            float v = acc[i][j];
            if (bias) v += bias[col0 + tx * 4 + j];
            if (rrow) v += rrow[j];
            orow[j] = v;
        }
    }
}

// ---------------------------------------------------------------- grad = km^T @ diff / C (per batch)
__global__ __launch_bounds__(256) void gemm_tn_kernel(
    const float* __restrict__ Am,   // (B*C) x D, accessed transposed
    const float* __restrict__ Bm,   // (B*C) x D
    float* __restrict__ out,        // B x D x D
    float scale)
{
    __shared__ float As[16][64];
    __shared__ float Bs[16][64];
    int b = blockIdx.z;
    int col0 = blockIdx.x * 64;
    int row0 = blockIdx.y * 64;
    int t = threadIdx.x, tx = t & 15, ty = t >> 4;
    const float* Ab = Am + (long long)b * C_ * D_;
    const float* Bb = Bm + (long long)b * C_ * D_;
    float acc[4][4] = {};
    for (int k0 = 0; k0 < C_; k0 += 16) {
        {
            int kk = t >> 4, m4 = (t & 15) * 4;
            *(float4*)&As[kk][m4] = *(const float4*)(Ab + (long long)(k0 + kk) * D_ + row0 + m4);
        }
        {
            int kk = t >> 4, n4 = (t & 15) * 4;
            *(float4*)&Bs[kk][n4] = *(const float4*)(Bb + (long long)(k0 + kk) * D_ + col0 + n4);
        }
        __syncthreads();
        #pragma unroll
        for (int kk = 0; kk < 16; kk++) {
            float a[4], b4[4];
            #pragma unroll
            for (int i = 0; i < 4; i++) a[i] = As[kk][ty * 4 + i];
            #pragma unroll
            for (int j = 0; j < 4; j++) b4[j] = Bs[kk][tx * 4 + j];
            #pragma unroll
            for (int i = 0; i < 4; i++)
                #pragma unroll
                for (int j = 0; j < 4; j++) acc[i][j] += a[i] * b4[j];
        }
        __syncthreads();
    }
    float* ob = out + (long long)b * D_ * D_;
    #pragma unroll
    for (int i = 0; i < 4; i++) {
        int m = row0 + ty * 4 + i;
        #pragma unroll
        for (int j = 0; j < 4; j++)
            ob[(long long)m * D_ + col0 + tx * 4 + j] = acc[i][j] * scale;
    }
}

// ---------------------------------------------------------------- elementwise kernels
__global__ __launch_bounds__(256) void sub_kernel(float* __restrict__ a, const float* __restrict__ b, long long n)
{
    long long i = (long long)blockIdx.x * 256 + threadIdx.x;
    if (i < n) a[i] -= b[i];
}

__global__ __launch_bounds__(256) void update_mem_kernel(
    float* __restrict__ M, float* __restrict__ St, const float* __restrict__ grad,
    const float* __restrict__ lr, const float* __restrict__ mom, const float* __restrict__ fg,
    long long n)
{
    long long i = (long long)blockIdx.x * 256 + threadIdx.x;
    if (i >= n) return;
    float theta = sigmoidf_(lr[0]);
    float eta   = sigmoidf_(mom[0]);
    float alpha = sigmoidf_(fg[0]);
    float st = eta * St[i] - theta * grad[i];
    St[i] = st;
    M[i] = (1.0f - alpha) * M[i] + st;
}

__global__ __launch_bounds__(256) void gate_combine_kernel(
    const float* __restrict__ xc, long long xBatchStride,
    const float* __restrict__ gbuf, const float* __restrict__ aoW,
    const float* __restrict__ mctx, float* __restrict__ o)
{
    long long i = (long long)blockIdx.x * 256 + threadIdx.x;
    if (i >= (long long)B_ * C_ * D_) return;
    int row = (int)(i >> 10);
    int c = (int)(i & 1023);
    int bb = row >> 9, s = row & 511;
    float g = sigmoidf_(gbuf[i]);
    float xv = xc[(long long)bb * xBatchStride + (long long)s * D_ + c];
    o[i] = xv + g * aoW[i] + (1.0f - g) * mctx[i];
}

__global__ __launch_bounds__(256) void silu_mul_kernel(float* __restrict__ a, const float* __restrict__ b, long long n)
{
    long long i = (long long)blockIdx.x * 256 + threadIdx.x;
    if (i < n) {
        float v = a[i];
        a[i] = (v / (1.0f + expf(-v))) * b[i];
    }
}

// ---------------------------------------------------------------- attention
// grid (C/16, H, B), block 256. 16 queries/block, 528 keys (16 persistent + 512 chunk).
__global__ __launch_bounds__(256) void attn_kernel(
    const float* __restrict__ qh, const float* __restrict__ kh, const float* __restrict__ vh,
    const float* __restrict__ pk, const float* __restrict__ pv,
    float* __restrict__ ao)
{
    __shared__ float qs[16][64];
    __shared__ float sc[16][528];
    __shared__ float kv[64][64];
    int qt = blockIdx.x, h = blockIdx.y, b = blockIdx.z;
    int t = threadIdx.x;
    int q0 = qt * 16;
    for (int i = t; i < 16 * 64; i += 256) {
        int q = i >> 6, d = i & 63;
        qs[q][d] = qh[(long long)(b * C_ + q0 + q) * (H_ * DH_) + h * DH_ + d];
    }
    __syncthreads();
    // ---- persistent keys
    for (int i = t; i < P_ * 64; i += 256) {
        int k = i >> 6, d = i & 63;
        kv[k][d] = pk[((long long)k * H_ + h) * DH_ + d];
    }
    __syncthreads();
    {
        int q = t >> 4, k = t & 15;
        float s = 0.f;
        #pragma unroll 16
        for (int d = 0; d < 64; d++) s += qs[q][d] * kv[k][d];
        sc[q][k] = s * 0.125f;
    }
    __syncthreads();
    // ---- chunk keys, 8 tiles of 64
    for (int kt = 0; kt < 8; kt++) {
        for (int i = t; i < 64 * 64; i += 256) {
            int k = i >> 6, d = i & 63;
            kv[k][d] = kh[(long long)(b * C_ + kt * 64 + k) * (H_ * DH_) + h * DH_ + d];
        }
        __syncthreads();
        int q = t >> 4;
        int kb = t & 15;
        #pragma unroll
        for (int kk = 0; kk < 4; kk++) {
            int k = kb + kk * 16;
            float s = 0.f;
            #pragma unroll 16
            for (int d = 0; d < 64; d++) s += qs[q][d] * kv[k][d];
            int kg = kt * 64 + k;
            sc[q][P_ + kg] = (kg <= q0 + (t >> 4)) ? s * 0.125f : -1e9f;
        }
        __syncthreads();
    }
    // ---- softmax (16 threads per query)
    int q = t >> 4, lane = t & 15;
    float mx = -1e30f;
    for (int k = lane; k < P_ + C_; k += 16) mx = fmaxf(mx, sc[q][k]);
    #pragma unroll
    for (int off = 8; off >= 1; off >>= 1) mx = fmaxf(mx, __shfl_xor(mx, off, 16));
    float sum = 0.f;
    for (int k = lane; k < P_ + C_; k += 16) {
        float e = expf(sc[q][k] - mx);
        sc[q][k] = e;
        sum += e;
    }
    #pragma unroll
    for (int off = 8; off >= 1; off >>= 1) sum += __shfl_xor(sum, off, 16);
    float inv = 1.0f / sum;
    __syncthreads();
    // ---- output: thread handles (q, dims lane*4..+3)
    float acc[4] = {0.f, 0.f, 0.f, 0.f};
    for (int i = t; i < P_ * 64; i += 256) {
        int k = i >> 6, d = i & 63;
        kv[k][d] = pv[((long long)k * H_ + h) * DH_ + d];
    }
    __syncthreads();
    for (int k = 0; k < P_; k++) {
        float a = sc[q][k] * inv;
        #pragma unroll
        for (int j = 0; j < 4; j++) acc[j] += a * kv[k][lane * 4 + j];
    }
    __syncthreads();
    for (int kt = 0; kt < 8; kt++) {
        for (int i = t; i < 64 * 64; i += 256) {
            int k = i >> 6, d = i & 63;
            kv[k][d] = vh[(long long)(b * C_ + kt * 64 + k) * (H_ * DH_) + h * DH_ + d];
        }
        __syncthreads();
        for (int k = 0; k < 64; k++) {
            float a = sc[q][P_ + kt * 64 + k] * inv;
            #pragma unroll
            for (int j = 0; j < 4; j++) acc[j] += a * kv[k][lane * 4 + j];
        }
        __syncthreads();
    }
    float* aop = ao + (long long)(b * C_ + q0 + q) * (H_ * DH_) + h * DH_ + lane * 4;
    #pragma unroll
    for (int j = 0; j < 4; j++) aop[j] = acc[j];
}

// ---------------------------------------------------------------- launch
extern "C" void kernel_launch(void* const* d_in, const int* in_sizes, int n_in,
                              void* d_out, int out_size, void* d_ws, size_t ws_size,
                              hipStream_t stream)
{
    const float* x     = (const float*)d_in[0];
    const float* g1    = (const float*)d_in[1];
    const float* b1    = (const float*)d_in[2];
    const float* g2    = (const float*)d_in[3];
    const float* b2    = (const float*)d_in[4];
    const float* g3    = (const float*)d_in[5];
    const float* b3    = (const float*)d_in[6];
    const float* Wqm   = (const float*)d_in[7];
    const float* Wkm   = (const float*)d_in[8];
    const float* Wvm   = (const float*)d_in[9];
    const float* lr    = (const float*)d_in[10];
    const float* mom   = (const float*)d_in[11];
    const float* fg    = (const float*)d_in[12];
    const float* Wq    = (const float*)d_in[13];
    const float* bq    = (const float*)d_in[14];
    const float* Wk    = (const float*)d_in[15];
    const float* bk    = (const float*)d_in[16];
    const float* Wv    = (const float*)d_in[17];
    const float* bv    = (const float*)d_in[18];
    const float* Wo    = (const float*)d_in[19];
    const float* bo    = (const float*)d_in[20];
    const float* pk    = (const float*)d_in[21];
    const float* pv    = (const float*)d_in[22];
    const float* Wg    = (const float*)d_in[23];
    const float* bg    = (const float*)d_in[24];
    const float* Wgate = (const float*)d_in[25];
    const float* bgate = (const float*)d_in[26];
    const float* Wup   = (const float*)d_in[27];
    const float* bup   = (const float*)d_in[28];
    const float* Wdown = (const float*)d_in[29];
    const float* bdown = (const float*)d_in[30];
    float* out = (float*)d_out;
    float* ws  = (float*)d_ws;

    // arena (floats): M[4M] St[4M] slots A..H [2M each] big[16M]
    const long long MFl = 4194304LL;   // 4M floats
    const long long SL  = 2097152LL;   // 2M floats
    float* M   = ws;
    float* St  = ws + MFl;
    float* sA  = ws + 2 * MFl;
    float* sB  = sA + SL;
    float* sC  = sB + SL;
    float* sD  = sC + SL;
    float* sE  = sD + SL;
    float* sF  = sE + SL;
    float* sG  = sF + SL;
    float* sH  = sG + SL;
    float* big = sH + SL;              // 16M floats (grad reuses front 4M)

    // zero M and St (ws is poisoned before each call)
    hipMemsetAsync(ws, 0, (size_t)(2 * MFl) * sizeof(float), stream);

    const long long xBS = (long long)S_ * D_;         // x batch stride
    const long long flatBS = (long long)C_ * D_;      // flat activation "batch stride"
    const long long flatFF = (long long)C_ * FF_;
    const dim3 g1024(D_ / 64, (B_ * C_) / 64);        // N=1024 GEMM grid
    const dim3 g4096(FF_ / 64, (B_ * C_) / 64);       // N=4096 GEMM grid

    for (int ci = 0; ci < NC_; ci++) {
        const float* xchunk = x + (long long)ci * C_ * D_;
        float* ochunk = out + (long long)ci * C_ * D_;

        // 1) h1 = LN1(xc)                                  -> sA
        ln_kernel<<<B_ * C_, 256, 0, stream>>>(xchunk, xBS, C_, nullptr, g1, b1, sA);
        // 2-4) qm, km, vm                                  -> sB, sC, sD
        gemm_kernel<<<g1024, 256, 0, stream>>>(sA, Wqm, nullptr, nullptr, sB, D_, D_, 0, C_, flatBS);
        gemm_kernel<<<g1024, 256, 0, stream>>>(sA, Wkm, nullptr, nullptr, sC, D_, D_, 0, C_, flatBS);
        gemm_kernel<<<g1024, 256, 0, stream>>>(sA, Wvm, nullptr, nullptr, sD, D_, D_, 0, C_, flatBS);
        // 5) km row-normalize
        rownorm_kernel<<<B_ * C_, 256, 0, stream>>>(sC);
        // 6) mem_ctx = qm @ M[b]                           -> sE
        gemm_kernel<<<g1024, 256, 0, stream>>>(sB, M, nullptr, nullptr, sE, D_, D_, (long long)D_ * D_, C_, flatBS);
        // 7) pred = km @ M[b]                              -> sF
        gemm_kernel<<<g1024, 256, 0, stream>>>(sC, M, nullptr, nullptr, sF, D_, D_, (long long)D_ * D_, C_, flatBS);
        // 8) diff = pred - vm                              (in sF)
        sub_kernel<<<(B_ * C_ * D_) / 256, 256, 0, stream>>>(sF, sD, (long long)B_ * C_ * D_);
        // 9) grad = km^T @ diff / C                        -> big
        gemm_tn_kernel<<<dim3(D_ / 64, D_ / 64, B_), 256, 0, stream>>>(sC, sF, big, 1.0f / C_);
        // 10) St = eta*St - theta*grad ; M = (1-a)*M + St
        update_mem_kernel<<<(B_ * D_ * D_) / 256, 256, 0, stream>>>(M, St, big, lr, mom, fg, (long long)B_ * D_ * D_);
        // 11) h2 = LN2(xc + mem_ctx)                       -> sA
        ln_kernel<<<B_ * C_, 256, 0, stream>>>(xchunk, xBS, C_, sE, g2, b2, sA);
        // 12-14) qh, kh, vh                                -> sB, sC, sD
        gemm_kernel<<<g1024, 256, 0, stream>>>(sA, Wq, bq, nullptr, sB, D_, D_, 0, C_, flatBS);
        gemm_kernel<<<g1024, 256, 0, stream>>>(sA, Wk, bk, nullptr, sC, D_, D_, 0, C_, flatBS);
        gemm_kernel<<<g1024, 256, 0, stream>>>(sA, Wv, bv, nullptr, sD, D_, D_, 0, C_, flatBS);
        // 15) attention                                    -> sF
        attn_kernel<<<dim3(C_ / 16, H_, B_), 256, 0, stream>>>(sB, sC, sD, pk, pv, sF);
        // 16) aoW = ao @ Wo + bo                           -> sG
        gemm_kernel<<<g1024, 256, 0, stream>>>(sF, Wo, bo, nullptr, sG, D_, D_, 0, C_, flatBS);
        // 17) gbuf = mem_ctx @ Wg + bg                     -> sH
        gemm_kernel<<<g1024, 256, 0, stream>>>(sE, Wg, bg, nullptr, sH, D_, D_, 0, C_, flatBS);
        // 18) o = xc + sig(gbuf)*aoW + (1-sig)*mem_ctx     -> sA
        gate_combine_kernel<<<(B_ * C_ * D_) / 256, 256, 0, stream>>>(xchunk, xBS, sH, sG, sE, sA);
        // 19) h3 = LN3(o)                                  -> sB
        ln_kernel<<<B_ * C_, 256, 0, stream>>>(sA, flatBS, C_, nullptr, g3, b3, sB);
        // 20-21) gate, up                                  -> big, big+8M
        gemm_kernel<<<g4096, 256, 0, stream>>>(sB, Wgate, bgate, nullptr, big, D_, FF_, 0, C_, flatFF);
        gemm_kernel<<<g4096, 256, 0, stream>>>(sB, Wup, bup, nullptr, big + 2 * MFl, D_, FF_, 0, C_, flatFF);
        // 22) prod = silu(gate)*up                         (in big)
        silu_mul_kernel<<<(B_ * C_ * FF_) / 256, 256, 0, stream>>>(big, big + 2 * MFl, (long long)B_ * C_ * FF_);
        // 23) out = o + prod @ Wdown + bdown               -> d_out (batch-mapped)
        gemm_kernel<<<g1024, 256, 0, stream>>>(big, Wdown, bdown, sA, ochunk, FF_, D_, 0, C_, xBS);
    }
}

// Round 2
// 7177.810 us; speedup vs baseline: 2.5814x; 2.5814x over previous
//
#include <hip/hip_runtime.h>
#include <hip/hip_bf16.h>
#include <math.h>

#define D_ 1024
#define C_ 512
#define H_ 16
#define DH_ 64
#define P_ 16
#define FF_ 4096
#define S_ 4096
#define B_ 4
#define NC_ 8

typedef __attribute__((ext_vector_type(8))) short short8;
typedef __attribute__((ext_vector_type(4))) float floatx4;

__device__ __forceinline__ float sigmoidf_(float x) { return 1.0f / (1.0f + expf(-x)); }
__device__ __forceinline__ unsigned short f2b(float x) {
    __hip_bfloat16 h = __float2bfloat16(x);
    return __builtin_bit_cast(unsigned short, h);
}
__device__ __forceinline__ float b2f(unsigned short u) {
    __hip_bfloat16 h = __builtin_bit_cast(__hip_bfloat16, u);
    return __bfloat162float(h);
}

// ---------------------------------------------------------------- LayerNorm (fp32 in, bf16 out)
__global__ __launch_bounds__(256) void ln_kernel(
    const float* __restrict__ x, long long xBatchStride, int rowsPerBatch,
    const float* __restrict__ add,
    const float* __restrict__ g, const float* __restrict__ beta,
    unsigned short* __restrict__ out)
{
    __shared__ float sbuf[4];
    int row = blockIdx.x;
    int bb = row / rowsPerBatch, s = row - bb * rowsPerBatch;
    const float* xr = x + (long long)bb * xBatchStride + (long long)s * D_;
    int t = threadIdx.x;
    float v[4];
    float4 xv = *(const float4*)(xr + t * 4);
    v[0] = xv.x; v[1] = xv.y; v[2] = xv.z; v[3] = xv.w;
    if (add) {
        float4 av = *(const float4*)(add + (long long)row * D_ + t * 4);
        v[0] += av.x; v[1] += av.y; v[2] += av.z; v[3] += av.w;
    }
    float ls = v[0] + v[1] + v[2] + v[3];
    #pragma unroll
    for (int off = 32; off >= 1; off >>= 1) ls += __shfl_down(ls, off, 64);
    if ((t & 63) == 0) sbuf[t >> 6] = ls;
    __syncthreads();
    float mean = (sbuf[0] + sbuf[1] + sbuf[2] + sbuf[3]) * (1.0f / D_);
    __syncthreads();
    float lv = 0.f;
    #pragma unroll
    for (int i = 0; i < 4; i++) { float d = v[i] - mean; lv += d * d; }
    #pragma unroll
    for (int off = 32; off >= 1; off >>= 1) lv += __shfl_down(lv, off, 64);
    if ((t & 63) == 0) sbuf[t >> 6] = lv;
    __syncthreads();
    float var = (sbuf[0] + sbuf[1] + sbuf[2] + sbuf[3]) * (1.0f / D_);
    float r = rsqrtf(var + 1e-5f);
    unsigned short* orow = out + (long long)row * D_;
    #pragma unroll
    for (int i = 0; i < 4; i++) {
        int c = t * 4 + i;
        orow[c] = f2b((v[i] - mean) * r * g[c] + beta[c]);
    }
}

// ---------------------------------------------------------------- km row L2-normalize (fp32 in, bf16 out)
__global__ __launch_bounds__(256) void rownorm_kernel(const float* __restrict__ a, unsigned short* __restrict__ out)
{
    __shared__ float sbuf[4];
    int row = blockIdx.x;
    int t = threadIdx.x;
    const float* ar = a + (long long)row * D_;
    float4 xv = *(const float4*)(ar + t * 4);
    float ls = xv.x * xv.x + xv.y * xv.y + xv.z * xv.z + xv.w * xv.w;
    #pragma unroll
    for (int off = 32; off >= 1; off >>= 1) ls += __shfl_down(ls, off, 64);
    if ((t & 63) == 0) sbuf[t >> 6] = ls;
    __syncthreads();
    float ss = sbuf[0] + sbuf[1] + sbuf[2] + sbuf[3];
    float sc = rsqrtf(ss + 1e-6f);
    unsigned short* orow = out + (long long)row * D_;
    orow[t * 4 + 0] = f2b(xv.x * sc);
    orow[t * 4 + 1] = f2b(xv.y * sc);
    orow[t * 4 + 2] = f2b(xv.z * sc);
    orow[t * 4 + 3] = f2b(xv.w * sc);
}

// ---------------------------------------------------------------- transposes (tiled, LDS)
// fp32 [R][Cc] -> bf16 [Cc][R]
__global__ __launch_bounds__(256) void transpose_f32_b16(
    const float* __restrict__ in, unsigned short* __restrict__ out,
    int R, int Cc, long long izs, long long ozs)
{
    __shared__ float tile[32][33];
    int z = blockIdx.z;
    const float* ib = in + (long long)z * izs;
    unsigned short* ob = out + (long long)z * ozs;
    int c0 = blockIdx.x * 32, r0 = blockIdx.y * 32;
    int tx = threadIdx.x & 31, ty = threadIdx.x >> 5;
    #pragma unroll
    for (int i = 0; i < 32; i += 8)
        tile[ty + i][tx] = ib[(long long)(r0 + ty + i) * Cc + c0 + tx];
    __syncthreads();
    #pragma unroll
    for (int i = 0; i < 32; i += 8)
        ob[(long long)(c0 + ty + i) * R + r0 + tx] = f2b(tile[tx][ty + i]);
}

// bf16 [R][Cc] -> bf16 [Cc][R]
__global__ __launch_bounds__(256) void transpose_b16_b16(
    const unsigned short* __restrict__ in, unsigned short* __restrict__ out,
    int R, int Cc, long long izs, long long ozs)
{
    __shared__ unsigned short tile[32][33];
    int z = blockIdx.z;
    const unsigned short* ib = in + (long long)z * izs;
    unsigned short* ob = out + (long long)z * ozs;
    int c0 = blockIdx.x * 32, r0 = blockIdx.y * 32;
    int tx = threadIdx.x & 31, ty = threadIdx.x >> 5;
    #pragma unroll
    for (int i = 0; i < 32; i += 8)
        tile[ty + i][tx] = ib[(long long)(r0 + ty + i) * Cc + c0 + tx];
    __syncthreads();
    #pragma unroll
    for (int i = 0; i < 32; i += 8)
        ob[(long long)(c0 + ty + i) * R + r0 + tx] = tile[tx][ty + i];
}

// diffT[z][d][t] = bf16(pred[z][t][d] - vm[z][t][d])
__global__ __launch_bounds__(256) void subT_kernel(
    const float* __restrict__ pred, const float* __restrict__ vm, unsigned short* __restrict__ out)
{
    __shared__ float tile[32][33];
    int z = blockIdx.z;
    int c0 = blockIdx.x * 32, r0 = blockIdx.y * 32;
    int tx = threadIdx.x & 31, ty = threadIdx.x >> 5;
    const float* pb = pred + (long long)z * C_ * D_;
    const float* vb = vm + (long long)z * C_ * D_;
    #pragma unroll
    for (int i = 0; i < 32; i += 8) {
        long long idx = (long long)(r0 + ty + i) * D_ + c0 + tx;
        tile[ty + i][tx] = pb[idx] - vb[idx];
    }
    __syncthreads();
    unsigned short* ob = out + (long long)z * D_ * C_;
    #pragma unroll
    for (int i = 0; i < 32; i += 8)
        ob[(long long)(c0 + ty + i) * C_ + r0 + tx] = f2b(tile[tx][ty + i]);
}

// ---------------------------------------------------------------- bf16 MFMA GEMM
// C[z][m][n] = A[z][m][:] @ BT[z][n][:]^T (+bias) (+resid), out fp32 and/or bf16.
// Tile 128(M) x 64(N) x 32(K); 256 threads = 4 waves, each wave 64x32 via 4x2
// mfma_f32_16x16x32_bf16. BT is the weight stored transposed [N][K].
__global__ __launch_bounds__(256) void gemm_mfma(
    const unsigned short* __restrict__ A, const unsigned short* __restrict__ BT,
    const float* __restrict__ bias, const float* __restrict__ resid,
    float* __restrict__ outF, unsigned short* __restrict__ outB,
    int K, int N,
    long long Azs, long long Bzs, long long Rzs, long long Ozs)
{
    __shared__ __align__(16) short As[128][40];   // pitch 40 shorts = 80 B (2-way max conflicts)
    __shared__ __align__(16) short Bs[64][40];
    int z = blockIdx.z;
    const short* Ab = (const short*)A + (long long)z * Azs;
    const short* Bb = (const short*)BT + (long long)z * Bzs;
    int row0 = blockIdx.y * 128, col0 = blockIdx.x * 64;
    int t = threadIdx.x;
    int wave = t >> 6, lane = t & 63;
    int quad = lane >> 4, lo = lane & 15;
    int moff = (wave & 1) * 64, noff = (wave >> 1) * 32;
    floatx4 acc[4][2];
    #pragma unroll
    for (int i = 0; i < 4; i++)
        #pragma unroll
        for (int j = 0; j < 2; j++) acc[i][j] = (floatx4){0.f, 0.f, 0.f, 0.f};

    int sr = t >> 2;          // staging row 0..63
    int sk = (t & 3) * 8;     // staging k offset (shorts)

    for (int k0 = 0; k0 < K; k0 += 32) {
        *(int4*)&As[sr][sk]      = *(const int4*)(Ab + (long long)(row0 + sr) * K + k0 + sk);
        *(int4*)&As[64 + sr][sk] = *(const int4*)(Ab + (long long)(row0 + 64 + sr) * K + k0 + sk);
        *(int4*)&Bs[sr][sk]      = *(const int4*)(Bb + (long long)(col0 + sr) * K + k0 + sk);
        __syncthreads();
        short8 a[4], b[2];
        #pragma unroll
        for (int i = 0; i < 4; i++) a[i] = *(const short8*)&As[moff + i * 16 + lo][quad * 8];
        #pragma unroll
        for (int j = 0; j < 2; j++) b[j] = *(const short8*)&Bs[noff + j * 16 + lo][quad * 8];
        #pragma unroll
        for (int i = 0; i < 4; i++)
            #pragma unroll
            for (int j = 0; j < 2; j++)
                acc[i][j] = __builtin_amdgcn_mfma_f32_16x16x32_bf16(a[i], b[j], acc[i][j], 0, 0, 0);
        __syncthreads();
    }
    #pragma unroll
    for (int i = 0; i < 4; i++)
        #pragma unroll
        for (int j = 0; j < 2; j++) {
            int col = col0 + noff + j * 16 + lo;
            float bv = bias ? bias[col] : 0.f;
            #pragma unroll
            for (int r = 0; r < 4; r++) {
                int row = row0 + moff + i * 16 + quad * 4 + r;
                long long idx = (long long)row * N + col;
                float v = acc[i][j][r] + bv;
                if (resid) v += resid[(long long)z * Rzs + idx];
                if (outF) outF[(long long)z * Ozs + idx] = v;
                if (outB) outB[(long long)z * Ozs + idx] = f2b(v);
            }
        }
}

// ---------------------------------------------------------------- elementwise
__global__ __launch_bounds__(256) void update_mem_kernel(
    float* __restrict__ M, float* __restrict__ St, const float* __restrict__ grad,
    const float* __restrict__ lr, const float* __restrict__ mom, const float* __restrict__ fg,
    long long n)
{
    long long i = (long long)blockIdx.x * 256 + threadIdx.x;
    if (i >= n) return;
    float theta = sigmoidf_(lr[0]) * (1.0f / C_);   // fold /C of grad
    float eta   = sigmoidf_(mom[0]);
    float alpha = sigmoidf_(fg[0]);
    float st = eta * St[i] - theta * grad[i];
    St[i] = st;
    M[i] = (1.0f - alpha) * M[i] + st;
}

__global__ __launch_bounds__(256) void gate_combine_kernel(
    const float* __restrict__ xc, long long xBatchStride,
    const float* __restrict__ gbuf, const float* __restrict__ aoW,
    const float* __restrict__ mctx, float* __restrict__ o)
{
    long long i = (long long)blockIdx.x * 256 + threadIdx.x;
    if (i >= (long long)B_ * C_ * D_) return;
    int row = (int)(i >> 10);
    int c = (int)(i & 1023);
    int bb = row >> 9, s = row & 511;
    float g = sigmoidf_(gbuf[i]);
    float xv = xc[(long long)bb * xBatchStride + (long long)s * D_ + c];
    o[i] = xv + g * aoW[i] + (1.0f - g) * mctx[i];
}

// a <- bf16(silu(a) * b), 8 elements/thread
__global__ __launch_bounds__(256) void silu_mul_b16(
    unsigned short* __restrict__ a, const unsigned short* __restrict__ b, long long n8)
{
    long long i = (long long)blockIdx.x * 256 + threadIdx.x;
    if (i >= n8) return;
    int4 av = ((const int4*)a)[i];
    int4 bv = ((const int4*)b)[i];
    unsigned short* ap = (unsigned short*)&av;
    const unsigned short* bp = (const unsigned short*)&bv;
    #pragma unroll
    for (int j = 0; j < 8; j++) {
        float x = b2f(ap[j]);
        float y = b2f(bp[j]);
        ap[j] = f2b((x / (1.0f + expf(-x))) * y);
    }
    ((int4*)a)[i] = av;
}

// ---------------------------------------------------------------- attention (fp32, conflict-free LDS)
__global__ __launch_bounds__(256) void attn_kernel(
    const float* __restrict__ qh, const float* __restrict__ kh, const float* __restrict__ vh,
    const float* __restrict__ pk, const float* __restrict__ pv,
    unsigned short* __restrict__ ao)
{
    __shared__ float qs[16][64];
    __shared__ float sc[16][528];
    __shared__ float kv[64][65];   // pad 65: bank = (k+d)%32, conflict-free
    int qt = blockIdx.x, h = blockIdx.y, b = blockIdx.z;
    int t = threadIdx.x;
    int q0 = qt * 16;
    for (int i = t; i < 16 * 64; i += 256) {
        int q = i >> 6, d = i & 63;
        qs[q][d] = qh[(long long)(b * C_ + q0 + q) * (H_ * DH_) + h * DH_ + d];
    }
    __syncthreads();
    for (int i = t; i < P_ * 64; i += 256) {
        int k = i >> 6, d = i & 63;
        kv[k][d] = pk[((long long)k * H_ + h) * DH_ + d];
    }
    __syncthreads();
    {
        int q = t >> 4, k = t & 15;
        float s = 0.f;
        #pragma unroll 16
        for (int d = 0; d < 64; d++) s += qs[q][d] * kv[k][d];
        sc[q][k] = s * 0.125f;
    }
    __syncthreads();
    for (int kt = 0; kt < 8; kt++) {
        for (int i = t; i < 64 * 64; i += 256) {
            int k = i >> 6, d = i & 63;
            kv[k][d] = kh[(long long)(b * C_ + kt * 64 + k) * (H_ * DH_) + h * DH_ + d];
        }
        __syncthreads();
        int q = t >> 4;
        int kb = t & 15;
        #pragma unroll
        for (int kk = 0; kk < 4; kk++) {
            int k = kb + kk * 16;
            float s = 0.f;
            #pragma unroll 16
            for (int d = 0; d < 64; d++) s += qs[q][d] * kv[k][d];
            int kg = kt * 64 + k;
            sc[q][P_ + kg] = (kg <= q0 + q) ? s * 0.125f : -1e9f;
        }
        __syncthreads();
    }
    int q = t >> 4, lane = t & 15;
    float mx = -1e30f;
    for (int k = lane; k < P_ + C_; k += 16) mx = fmaxf(mx, sc[q][k]);
    #pragma unroll
    for (int off = 8; off >= 1; off >>= 1) mx = fmaxf(mx, __shfl_xor(mx, off, 16));
    float sum = 0.f;
    for (int k = lane; k < P_ + C_; k += 16) {
        float e = expf(sc[q][k] - mx);
        sc[q][k] = e;
        sum += e;
    }
    #pragma unroll
    for (int off = 8; off >= 1; off >>= 1) sum += __shfl_xor(sum, off, 16);
    float inv = 1.0f / sum;
    __syncthreads();
    float acc[4] = {0.f, 0.f, 0.f, 0.f};
    for (int i = t; i < P_ * 64; i += 256) {
        int k = i >> 6, d = i & 63;
        kv[k][d] = pv[((long long)k * H_ + h) * DH_ + d];
    }
    __syncthreads();
    for (int k = 0; k < P_; k++) {
        float a = sc[q][k] * inv;
        #pragma unroll
        for (int j = 0; j < 4; j++) acc[j] += a * kv[k][lane * 4 + j];
    }
    __syncthreads();
    for (int kt = 0; kt < 8; kt++) {
        for (int i = t; i < 64 * 64; i += 256) {
            int k = i >> 6, d = i & 63;
            kv[k][d] = vh[(long long)(b * C_ + kt * 64 + k) * (H_ * DH_) + h * DH_ + d];
        }
        __syncthreads();
        for (int k = 0; k < 64; k++) {
            float a = sc[q][P_ + kt * 64 + k] * inv;
            #pragma unroll
            for (int j = 0; j < 4; j++) acc[j] += a * kv[k][lane * 4 + j];
        }
        __syncthreads();
    }
    unsigned short* aop = ao + (long long)(b * C_ + q0 + q) * (H_ * DH_) + h * DH_ + lane * 4;
    #pragma unroll
    for (int j = 0; j < 4; j++) aop[j] = f2b(acc[j]);
}

// ---------------------------------------------------------------- launch
extern "C" void kernel_launch(void* const* d_in, const int* in_sizes, int n_in,
                              void* d_out, int out_size, void* d_ws, size_t ws_size,
                              hipStream_t stream)
{
    const float* x     = (const float*)d_in[0];
    const float* g1    = (const float*)d_in[1];
    const float* b1    = (const float*)d_in[2];
    const float* g2    = (const float*)d_in[3];
    const float* b2    = (const float*)d_in[4];
    const float* g3    = (const float*)d_in[5];
    const float* b3    = (const float*)d_in[6];
    const float* Wqm   = (const float*)d_in[7];
    const float* Wkm   = (const float*)d_in[8];
    const float* Wvm   = (const float*)d_in[9];
    const float* lr    = (const float*)d_in[10];
    const float* mom   = (const float*)d_in[11];
    const float* fg    = (const float*)d_in[12];
    const float* Wq    = (const float*)d_in[13];
    const float* bq    = (const float*)d_in[14];
    const float* Wk    = (const float*)d_in[15];
    const float* bk    = (const float*)d_in[16];
    const float* Wv    = (const float*)d_in[17];
    const float* bv    = (const float*)d_in[18];
    const float* Wo    = (const float*)d_in[19];
    const float* bo    = (const float*)d_in[20];
    const float* pk    = (const float*)d_in[21];
    const float* pv    = (const float*)d_in[22];
    const float* Wg    = (const float*)d_in[23];
    const float* bg    = (const float*)d_in[24];
    const float* Wgate = (const float*)d_in[25];
    const float* bgate = (const float*)d_in[26];
    const float* bup   = (const float*)d_in[28];
    const float* Wup   = (const float*)d_in[27];
    const float* Wdown = (const float*)d_in[29];
    const float* bdown = (const float*)d_in[30];
    float* out = (float*)d_out;

    // ---- arena (byte offsets), total 160 MB
    const long long MB = 1024LL * 1024LL;
    char* w = (char*)d_ws;
    float* M  = (float*)(w + 0 * MB);            // 16 MB
    float* St = (float*)(w + 16 * MB);           // 16 MB
    unsigned short* Mt = (unsigned short*)(w + 32 * MB);   // 8 MB (bf16, [z][1024][1024] = M^T)
    unsigned short* WqmT   = (unsigned short*)(w + 40 * MB);
    unsigned short* WkmT   = (unsigned short*)(w + 42 * MB);
    unsigned short* WvmT   = (unsigned short*)(w + 44 * MB);
    unsigned short* WqT    = (unsigned short*)(w + 46 * MB);
    unsigned short* WkT    = (unsigned short*)(w + 48 * MB);
    unsigned short* WvT    = (unsigned short*)(w + 50 * MB);
    unsigned short* WoT    = (unsigned short*)(w + 52 * MB);
    unsigned short* WgT    = (unsigned short*)(w + 54 * MB);
    unsigned short* WgateT = (unsigned short*)(w + 56 * MB);  // 8 MB
    unsigned short* WupT   = (unsigned short*)(w + 64 * MB);  // 8 MB
    unsigned short* WdownT = (unsigned short*)(w + 72 * MB);  // 8 MB
    float* F0 = (float*)(w + 80 * MB);           // 8 MB each
    float* F1 = (float*)(w + 88 * MB);
    float* F2 = (float*)(w + 96 * MB);
    float* F3 = (float*)(w + 104 * MB);
    unsigned short* H0 = (unsigned short*)(w + 112 * MB);    // 4 MB each
    unsigned short* H1 = (unsigned short*)(w + 116 * MB);
    unsigned short* H2 = (unsigned short*)(w + 120 * MB);
    unsigned short* H3 = (unsigned short*)(w + 124 * MB);
    unsigned short* G0 = (unsigned short*)(w + 128 * MB);    // 16 MB
    unsigned short* G1 = (unsigned short*)(w + 144 * MB);    // 16 MB

    hipMemsetAsync(d_ws, 0, (size_t)(32 * MB), stream);      // zero M, St

    // ---- weight transposes (fp32 [K][N] -> bf16 [N][K]) once per call
    transpose_f32_b16<<<dim3(32, 32, 1), 256, 0, stream>>>(Wqm, WqmT, D_, D_, 0, 0);
    transpose_f32_b16<<<dim3(32, 32, 1), 256, 0, stream>>>(Wkm, WkmT, D_, D_, 0, 0);
    transpose_f32_b16<<<dim3(32, 32, 1), 256, 0, stream>>>(Wvm, WvmT, D_, D_, 0, 0);
    transpose_f32_b16<<<dim3(32, 32, 1), 256, 0, stream>>>(Wq, WqT, D_, D_, 0, 0);
    transpose_f32_b16<<<dim3(32, 32, 1), 256, 0, stream>>>(Wk, WkT, D_, D_, 0, 0);
    transpose_f32_b16<<<dim3(32, 32, 1), 256, 0, stream>>>(Wv, WvT, D_, D_, 0, 0);
    transpose_f32_b16<<<dim3(32, 32, 1), 256, 0, stream>>>(Wo, WoT, D_, D_, 0, 0);
    transpose_f32_b16<<<dim3(32, 32, 1), 256, 0, stream>>>(Wg, WgT, D_, D_, 0, 0);
    transpose_f32_b16<<<dim3(128, 32, 1), 256, 0, stream>>>(Wgate, WgateT, D_, FF_, 0, 0);
    transpose_f32_b16<<<dim3(128, 32, 1), 256, 0, stream>>>(Wup, WupT, D_, FF_, 0, 0);
    transpose_f32_b16<<<dim3(32, 128, 1), 256, 0, stream>>>(Wdown, WdownT, FF_, D_, 0, 0);

    const long long xBS = (long long)S_ * D_;
    const long long flatD = (long long)C_ * D_;     // 512*1024
    const dim3 gAct(16, 16, 1);    // M=2048, N=1024
    const dim3 gMem(16, 4, 4);     // per-batch M=512, N=1024
    const dim3 gGrad(16, 8, 4);    // per-batch M=1024, N=1024, K=512
    const dim3 gFF(64, 16, 1);     // M=2048, N=4096
    const dim3 gDown(16, 4, 4);    // per-batch M=512, N=1024, K=4096

    for (int ci = 0; ci < NC_; ci++) {
        const float* xchunk = x + (long long)ci * C_ * D_;
        float* ochunk = out + (long long)ci * C_ * D_;

        // 1) h1 = LN1(xc) -> H0 (bf16)
        ln_kernel<<<B_ * C_, 256, 0, stream>>>(xchunk, xBS, C_, nullptr, g1, b1, H0);
        // 2) qm -> H1 (bf16 only)
        gemm_mfma<<<gAct, 256, 0, stream>>>(H0, WqmT, nullptr, nullptr, nullptr, H1, D_, D_, 0, 0, 0, 0);
        // 3) km -> F1 (fp32)
        gemm_mfma<<<gAct, 256, 0, stream>>>(H0, WkmT, nullptr, nullptr, F1, nullptr, D_, D_, 0, 0, 0, 0);
        // 4) vm -> F2 (fp32)
        gemm_mfma<<<gAct, 256, 0, stream>>>(H0, WvmT, nullptr, nullptr, F2, nullptr, D_, D_, 0, 0, 0, 0);
        // 5) km normalize -> H2 (bf16)
        rownorm_kernel<<<B_ * C_, 256, 0, stream>>>(F1, H2);
        // 6) kmT -> H3 [z][1024][512]
        transpose_b16_b16<<<dim3(32, 16, 4), 256, 0, stream>>>(H2, H3, C_, D_, flatD, flatD);
        // 7) Mt = bf16(M^T) per batch
        transpose_f32_b16<<<dim3(32, 32, 4), 256, 0, stream>>>(M, Mt, D_, D_, (long long)D_ * D_, (long long)D_ * D_);
        // 8) mem_ctx = qm @ M -> F0 (fp32) + H0 (bf16)
        gemm_mfma<<<gMem, 256, 0, stream>>>(H1, Mt, nullptr, nullptr, F0, H0, D_, D_, flatD, (long long)D_ * D_, 0, flatD);
        // 9) pred = km @ M -> F3
        gemm_mfma<<<gMem, 256, 0, stream>>>(H2, Mt, nullptr, nullptr, F3, nullptr, D_, D_, flatD, (long long)D_ * D_, 0, flatD);
        // 10) diffT = (pred - vm)^T -> H1 [z][1024][512]
        subT_kernel<<<dim3(32, 16, 4), 256, 0, stream>>>(F3, F2, H1);
        // 11) grad = kmT @ diffT^T -> F2:F3 (fp32, [z][1024][1024])
        gemm_mfma<<<gGrad, 256, 0, stream>>>(H3, H1, nullptr, nullptr, F2, nullptr, C_, D_,
                                             (long long)D_ * C_, (long long)D_ * C_, 0, (long long)D_ * D_);
        // 12) momentum + forget update
        update_mem_kernel<<<(B_ * D_ * D_) / 256, 256, 0, stream>>>(M, St, F2, lr, mom, fg, (long long)B_ * D_ * D_);
        // 13) h2 = LN2(xc + mem_ctx) -> H2
        ln_kernel<<<B_ * C_, 256, 0, stream>>>(xchunk, xBS, C_, F0, g2, b2, H2);
        // 14-15) qh, kh, vh (fp32)
        gemm_mfma<<<gAct, 256, 0, stream>>>(H2, WqT, bq, nullptr, F1, nullptr, D_, D_, 0, 0, 0, 0);
        gemm_mfma<<<gAct, 256, 0, stream>>>(H2, WkT, bk, nullptr, F2, nullptr, D_, D_, 0, 0, 0, 0);
        gemm_mfma<<<gAct, 256, 0, stream>>>(H2, WvT, bv, nullptr, F3, nullptr, D_, D_, 0, 0, 0, 0);
        // 16) attention -> H3 (bf16)
        attn_kernel<<<dim3(C_ / 16, H_, B_), 256, 0, stream>>>(F1, F2, F3, pk, pv, H3);
        // 17) aoW = ao @ Wo + bo -> F1
        gemm_mfma<<<gAct, 256, 0, stream>>>(H3, WoT, bo, nullptr, F1, nullptr, D_, D_, 0, 0, 0, 0);
        // 18) gbuf = mem_ctx @ Wg + bg -> F2
        gemm_mfma<<<gAct, 256, 0, stream>>>(H0, WgT, bg, nullptr, F2, nullptr, D_, D_, 0, 0, 0, 0);
        // 19) o = xc + sig(gbuf)*aoW + (1-sig)*mem_ctx -> F2 (in place over gbuf)
        gate_combine_kernel<<<(B_ * C_ * D_) / 256, 256, 0, stream>>>(xchunk, xBS, F2, F1, F0, F2);
        // 20) h3 = LN3(o) -> H2
        ln_kernel<<<B_ * C_, 256, 0, stream>>>(F2, flatD, C_, nullptr, g3, b3, H2);
        // 21-22) gate -> G0, up -> G1 (bf16)
        gemm_mfma<<<gFF, 256, 0, stream>>>(H2, WgateT, bgate, nullptr, nullptr, G0, D_, FF_, 0, 0, 0, 0);
        gemm_mfma<<<gFF, 256, 0, stream>>>(H2, WupT, bup, nullptr, nullptr, G1, D_, FF_, 0, 0, 0, 0);
        // 23) G0 <- silu(G0)*G1
        silu_mul_b16<<<((long long)B_ * C_ * FF_ / 8) / 256, 256, 0, stream>>>(G0, G1, (long long)B_ * C_ * FF_ / 8);
        // 24) out = o + prod @ Wdown + bdown
        gemm_mfma<<<gDown, 256, 0, stream>>>(G0, WdownT, bdown, F2, ochunk, nullptr, FF_, D_,
                                             (long long)C_ * FF_, 0, flatD, xBS);
    }
}

// Round 4
// 3982.989 us; speedup vs baseline: 4.6520x; 1.8021x over previous
//
#include <hip/hip_runtime.h>
#include <hip/hip_bf16.h>
#include <math.h>

#define D_ 1024
#define C_ 512
#define H_ 16
#define DH_ 64
#define P_ 16
#define FF_ 4096
#define S_ 4096
#define B_ 4
#define NC_ 8
#define KP_ 72   // LDS pitch (shorts) for attn tiles: 144 B rows, 16B-aligned, conflict-free

typedef __attribute__((ext_vector_type(8))) short short8;
typedef __attribute__((ext_vector_type(4))) float floatx4;

__device__ __forceinline__ float sigmoidf_(float x) { return 1.0f / (1.0f + expf(-x)); }
__device__ __forceinline__ unsigned short f2b(float x) {
    __hip_bfloat16 h = __float2bfloat16(x);
    return __builtin_bit_cast(unsigned short, h);
}
__device__ __forceinline__ float b2f(unsigned short u) {
    __hip_bfloat16 h = __builtin_bit_cast(__hip_bfloat16, u);
    return __bfloat162float(h);
}

// ---------------------------------------------------------------- LayerNorm (fp32 in, bf16 out)
__global__ __launch_bounds__(256) void ln_kernel(
    const float* __restrict__ x, long long xBatchStride, int rowsPerBatch,
    const float* __restrict__ add,
    const float* __restrict__ g, const float* __restrict__ beta,
    unsigned short* __restrict__ out)
{
    __shared__ float sbuf[4];
    int row = blockIdx.x;
    int bb = row / rowsPerBatch, s = row - bb * rowsPerBatch;
    const float* xr = x + (long long)bb * xBatchStride + (long long)s * D_;
    int t = threadIdx.x;
    float v[4];
    float4 xv = *(const float4*)(xr + t * 4);
    v[0] = xv.x; v[1] = xv.y; v[2] = xv.z; v[3] = xv.w;
    if (add) {
        float4 av = *(const float4*)(add + (long long)row * D_ + t * 4);
        v[0] += av.x; v[1] += av.y; v[2] += av.z; v[3] += av.w;
    }
    float ls = v[0] + v[1] + v[2] + v[3];
    #pragma unroll
    for (int off = 32; off >= 1; off >>= 1) ls += __shfl_down(ls, off, 64);
    if ((t & 63) == 0) sbuf[t >> 6] = ls;
    __syncthreads();
    float mean = (sbuf[0] + sbuf[1] + sbuf[2] + sbuf[3]) * (1.0f / D_);
    __syncthreads();
    float lv = 0.f;
    #pragma unroll
    for (int i = 0; i < 4; i++) { float d = v[i] - mean; lv += d * d; }
    #pragma unroll
    for (int off = 32; off >= 1; off >>= 1) lv += __shfl_down(lv, off, 64);
    if ((t & 63) == 0) sbuf[t >> 6] = lv;
    __syncthreads();
    float var = (sbuf[0] + sbuf[1] + sbuf[2] + sbuf[3]) * (1.0f / D_);
    float r = rsqrtf(var + 1e-5f);
    unsigned short* orow = out + (long long)row * D_;
    #pragma unroll
    for (int i = 0; i < 4; i++) {
        int c = t * 4 + i;
        orow[c] = f2b((v[i] - mean) * r * g[c] + beta[c]);
    }
}

// ---------------------------------------------------------------- km row L2-normalize (fp32 in, bf16 out)
__global__ __launch_bounds__(256) void rownorm_kernel(const float* __restrict__ a, unsigned short* __restrict__ out)
{
    __shared__ float sbuf[4];
    int row = blockIdx.x;
    int t = threadIdx.x;
    const float* ar = a + (long long)row * D_;
    float4 xv = *(const float4*)(ar + t * 4);
    float ls = xv.x * xv.x + xv.y * xv.y + xv.z * xv.z + xv.w * xv.w;
    #pragma unroll
    for (int off = 32; off >= 1; off >>= 1) ls += __shfl_down(ls, off, 64);
    if ((t & 63) == 0) sbuf[t >> 6] = ls;
    __syncthreads();
    float ss = sbuf[0] + sbuf[1] + sbuf[2] + sbuf[3];
    float sc = rsqrtf(ss + 1e-6f);
    unsigned short* orow = out + (long long)row * D_;
    orow[t * 4 + 0] = f2b(xv.x * sc);
    orow[t * 4 + 1] = f2b(xv.y * sc);
    orow[t * 4 + 2] = f2b(xv.z * sc);
    orow[t * 4 + 3] = f2b(xv.w * sc);
}

// ---------------------------------------------------------------- transposes (tiled, LDS)
__global__ __launch_bounds__(256) void transpose_f32_b16(
    const float* __restrict__ in, unsigned short* __restrict__ out,
    int R, int Cc, long long izs, long long ozs)
{
    __shared__ float tile[32][33];
    int z = blockIdx.z;
    const float* ib = in + (long long)z * izs;
    unsigned short* ob = out + (long long)z * ozs;
    int c0 = blockIdx.x * 32, r0 = blockIdx.y * 32;
    int tx = threadIdx.x & 31, ty = threadIdx.x >> 5;
    #pragma unroll
    for (int i = 0; i < 32; i += 8)
        tile[ty + i][tx] = ib[(long long)(r0 + ty + i) * Cc + c0 + tx];
    __syncthreads();
    #pragma unroll
    for (int i = 0; i < 32; i += 8)
        ob[(long long)(c0 + ty + i) * R + r0 + tx] = f2b(tile[tx][ty + i]);
}

__global__ __launch_bounds__(256) void transpose_b16_b16(
    const unsigned short* __restrict__ in, unsigned short* __restrict__ out,
    int R, int Cc, long long izs, long long ozs)
{
    __shared__ unsigned short tile[32][33];
    int z = blockIdx.z;
    const unsigned short* ib = in + (long long)z * izs;
    unsigned short* ob = out + (long long)z * ozs;
    int c0 = blockIdx.x * 32, r0 = blockIdx.y * 32;
    int tx = threadIdx.x & 31, ty = threadIdx.x >> 5;
    #pragma unroll
    for (int i = 0; i < 32; i += 8)
        tile[ty + i][tx] = ib[(long long)(r0 + ty + i) * Cc + c0 + tx];
    __syncthreads();
    #pragma unroll
    for (int i = 0; i < 32; i += 8)
        ob[(long long)(c0 + ty + i) * R + r0 + tx] = tile[tx][ty + i];
}

// diffT[z][d][t] = bf16(pred[z][t][d] - vm[z][t][d])
__global__ __launch_bounds__(256) void subT_kernel(
    const float* __restrict__ pred, const float* __restrict__ vm, unsigned short* __restrict__ out)
{
    __shared__ float tile[32][33];
    int z = blockIdx.z;
    int c0 = blockIdx.x * 32, r0 = blockIdx.y * 32;
    int tx = threadIdx.x & 31, ty = threadIdx.x >> 5;
    const float* pb = pred + (long long)z * C_ * D_;
    const float* vb = vm + (long long)z * C_ * D_;
    #pragma unroll
    for (int i = 0; i < 32; i += 8) {
        long long idx = (long long)(r0 + ty + i) * D_ + c0 + tx;
        tile[ty + i][tx] = pb[idx] - vb[idx];
    }
    __syncthreads();
    unsigned short* ob = out + (long long)z * D_ * C_;
    #pragma unroll
    for (int i = 0; i < 32; i += 8)
        ob[(long long)(c0 + ty + i) * C_ + r0 + tx] = f2b(tile[tx][ty + i]);
}

// ---------------------------------------------------------------- bf16 MFMA GEMM
// Tile 128(M) x 64(N) x 32(K); 256 threads = 4 waves, each wave 64x32 via 4x2
// mfma_f32_16x16x32_bf16. BT is the weight stored transposed [N][K].
__global__ __launch_bounds__(256) void gemm_mfma(
    const unsigned short* __restrict__ A, const unsigned short* __restrict__ BT,
    const float* __restrict__ bias, const float* __restrict__ resid,
    float* __restrict__ outF, unsigned short* __restrict__ outB,
    int K, int N,
    long long Azs, long long Bzs, long long Rzs, long long Ozs)
{
    __shared__ __align__(16) short As[128][40];
    __shared__ __align__(16) short Bs[64][40];
    int z = blockIdx.z;
    const short* Ab = (const short*)A + (long long)z * Azs;
    const short* Bb = (const short*)BT + (long long)z * Bzs;
    int row0 = blockIdx.y * 128, col0 = blockIdx.x * 64;
    int t = threadIdx.x;
    int wave = t >> 6, lane = t & 63;
    int quad = lane >> 4, lo = lane & 15;
    int moff = (wave & 1) * 64, noff = (wave >> 1) * 32;
    floatx4 acc[4][2];
    #pragma unroll
    for (int i = 0; i < 4; i++)
        #pragma unroll
        for (int j = 0; j < 2; j++) acc[i][j] = (floatx4){0.f, 0.f, 0.f, 0.f};

    int sr = t >> 2;
    int sk = (t & 3) * 8;

    for (int k0 = 0; k0 < K; k0 += 32) {
        *(int4*)&As[sr][sk]      = *(const int4*)(Ab + (long long)(row0 + sr) * K + k0 + sk);
        *(int4*)&As[64 + sr][sk] = *(const int4*)(Ab + (long long)(row0 + 64 + sr) * K + k0 + sk);
        *(int4*)&Bs[sr][sk]      = *(const int4*)(Bb + (long long)(col0 + sr) * K + k0 + sk);
        __syncthreads();
        short8 a[4], b[2];
        #pragma unroll
        for (int i = 0; i < 4; i++) a[i] = *(const short8*)&As[moff + i * 16 + lo][quad * 8];
        #pragma unroll
        for (int j = 0; j < 2; j++) b[j] = *(const short8*)&Bs[noff + j * 16 + lo][quad * 8];
        #pragma unroll
        for (int i = 0; i < 4; i++)
            #pragma unroll
            for (int j = 0; j < 2; j++)
                acc[i][j] = __builtin_amdgcn_mfma_f32_16x16x32_bf16(a[i], b[j], acc[i][j], 0, 0, 0);
        __syncthreads();
    }
    #pragma unroll
    for (int i = 0; i < 4; i++)
        #pragma unroll
        for (int j = 0; j < 2; j++) {
            int col = col0 + noff + j * 16 + lo;
            float bv = bias ? bias[col] : 0.f;
            #pragma unroll
            for (int r = 0; r < 4; r++) {
                int row = row0 + moff + i * 16 + quad * 4 + r;
                long long idx = (long long)row * N + col;
                float v = acc[i][j][r] + bv;
                if (resid) v += resid[(long long)z * Rzs + idx];
                if (outF) outF[(long long)z * Ozs + idx] = v;
                if (outB) outB[(long long)z * Ozs + idx] = f2b(v);
            }
        }
}

// ---------------------------------------------------------------- elementwise
__global__ __launch_bounds__(256) void update_mem_kernel(
    float* __restrict__ M, float* __restrict__ St, const float* __restrict__ grad,
    const float* __restrict__ lr, const float* __restrict__ mom, const float* __restrict__ fg,
    long long n)
{
    long long i = (long long)blockIdx.x * 256 + threadIdx.x;
    if (i >= n) return;
    float theta = sigmoidf_(lr[0]) * (1.0f / C_);
    float eta   = sigmoidf_(mom[0]);
    float alpha = sigmoidf_(fg[0]);
    float st = eta * St[i] - theta * grad[i];
    St[i] = st;
    M[i] = (1.0f - alpha) * M[i] + st;
}

__global__ __launch_bounds__(256) void gate_combine_kernel(
    const float* __restrict__ xc, long long xBatchStride,
    const float* __restrict__ gbuf, const float* __restrict__ aoW,
    const float* __restrict__ mctx, float* __restrict__ o)
{
    long long i = (long long)blockIdx.x * 256 + threadIdx.x;
    if (i >= (long long)B_ * C_ * D_) return;
    int row = (int)(i >> 10);
    int c = (int)(i & 1023);
    int bb = row >> 9, s = row & 511;
    float g = sigmoidf_(gbuf[i]);
    float xv = xc[(long long)bb * xBatchStride + (long long)s * D_ + c];
    o[i] = xv + g * aoW[i] + (1.0f - g) * mctx[i];
}

__global__ __launch_bounds__(256) void silu_mul_b16(
    unsigned short* __restrict__ a, const unsigned short* __restrict__ b, long long n8)
{
    long long i = (long long)blockIdx.x * 256 + threadIdx.x;
    if (i >= n8) return;
    int4 av = ((const int4*)a)[i];
    int4 bv = ((const int4*)b)[i];
    unsigned short* ap = (unsigned short*)&av;
    const unsigned short* bp = (const unsigned short*)&bv;
    #pragma unroll
    for (int j = 0; j < 8; j++) {
        float x = b2f(ap[j]);
        float y = b2f(bp[j]);
        ap[j] = f2b((x / (1.0f + expf(-x))) * y);
    }
    ((int4*)a)[i] = av;
}

// ---------------------------------------------------------------- MFMA flash attention
// grid (C_/64, H, B), 256 threads = 4 waves x 16 queries. Online softmax over
// tiles: kt=0 -> 16 persistent keys, kt=1..qb+1 -> 64 chunk keys (diag tile masked).
__global__ __launch_bounds__(256) void attn_mfma(
    const unsigned short* __restrict__ qh, const unsigned short* __restrict__ kh,
    const unsigned short* __restrict__ vh,
    const float* __restrict__ pk, const float* __restrict__ pv,
    unsigned short* __restrict__ ao)
{
    __shared__ __align__(16) short Ks[64][KP_];   // [key][d]   (QK^T B-operand)
    __shared__ __align__(16) short Vs[64][KP_];   // [d][key]   (PV B-operand)
    __shared__ __align__(16) short Ps[4][16][KP_];// per-wave P [q][key] (PV A-operand)
    int qb = blockIdx.x, h = blockIdx.y, b = blockIdx.z;
    int q0 = qb * 64;
    int t = threadIdx.x;
    int wave = t >> 6, lane = t & 63;
    int quad = lane >> 4, lo = lane & 15;

    // preload Q A-frags: lane holds Q row (q0 + wave*16 + lo), k = quad*8+j (+32)
    short8 qf[2];
    {
        const unsigned short* qp = qh + (long long)(b * C_ + q0 + wave * 16 + lo) * (H_ * DH_)
                                   + h * DH_ + quad * 8;
        qf[0] = *(const short8*)qp;
        qf[1] = *(const short8*)(qp + 32);
    }
    floatx4 o4[4];
    #pragma unroll
    for (int dt = 0; dt < 4; dt++) o4[dt] = (floatx4){0.f, 0.f, 0.f, 0.f};
    float m[4], l[4];
    #pragma unroll
    for (int r = 0; r < 4; r++) { m[r] = -1e30f; l[r] = 0.f; }
    // zero Ps cols 16..31 so persistent tile's k=32 MFMA A-operand sees zeros
    {
        short* pz = &Ps[wave][lo][16 + quad * 4];
        pz[0] = 0; pz[1] = 0; pz[2] = 0; pz[3] = 0;
    }

    int ktmax = qb + 1;
    for (int kt = 0; kt <= ktmax; kt++) {
        __syncthreads();
        if (kt == 0) {
            // persistent: 16 keys. thread: key = t>>4, d4 = (t&15)*4
            int key = t >> 4, d4 = (t & 15) * 4;
            float4 kv4 = *(const float4*)(pk + ((long long)key * H_ + h) * DH_ + d4);
            Ks[key][d4 + 0] = f2b(kv4.x); Ks[key][d4 + 1] = f2b(kv4.y);
            Ks[key][d4 + 2] = f2b(kv4.z); Ks[key][d4 + 3] = f2b(kv4.w);
            float4 vv4 = *(const float4*)(pv + ((long long)key * H_ + h) * DH_ + d4);
            Vs[d4 + 0][key] = f2b(vv4.x); Vs[d4 + 1][key] = f2b(vv4.y);
            Vs[d4 + 2][key] = f2b(vv4.z); Vs[d4 + 3][key] = f2b(vv4.w);
            // CRITICAL: zero Vs keys 16..31 for ALL dims. The kt=0 PV MFMA reads
            // them (quads 2-3); P=0 there, but 0 x LDS-garbage-NaN = NaN.
            int dz = t >> 2, kz = 16 + (t & 3) * 4;
            Vs[dz][kz + 0] = 0; Vs[dz][kz + 1] = 0;
            Vs[dz][kz + 2] = 0; Vs[dz][kz + 3] = 0;
        } else {
            int tok0 = (kt - 1) * 64;
            // K: thread key = t>>2, dims (t&3)*16..+15 (coalesced 128B/row)
            {
                int key = t >> 2, dblk = (t & 3) * 16;
                const unsigned short* kp2 = kh + (long long)(b * C_ + tok0 + key) * (H_ * DH_)
                                            + h * DH_ + dblk;
                *(short8*)&Ks[key][dblk]     = *(const short8*)kp2;
                *(short8*)&Ks[key][dblk + 8] = *(const short8*)(kp2 + 8);
            }
            // V transposed: thread handles keys (2kp,2kp+1), dims dg*8..+7; packed b32 writes
            {
                int kp = t & 31, dg = t >> 5;
                const unsigned short* vp0 = vh + (long long)(b * C_ + tok0 + 2 * kp) * (H_ * DH_)
                                            + h * DH_ + dg * 8;
                short8 v0 = *(const short8*)vp0;
                short8 v1 = *(const short8*)(vp0 + H_ * DH_);
                #pragma unroll
                for (int j = 0; j < 8; j++) {
                    unsigned int pk2 = ((unsigned int)(unsigned short)v1[j] << 16)
                                     | (unsigned short)v0[j];
                    *(unsigned int*)&Vs[dg * 8 + j][2 * kp] = pk2;
                }
            }
        }
        __syncthreads();

        int ntiles = (kt == 0) ? 1 : 4;
        // ---- S = Q K^T
        floatx4 s4[4];
        #pragma unroll
        for (int nt = 0; nt < 4; nt++) {
            if (nt >= ntiles) break;
            s4[nt] = (floatx4){0.f, 0.f, 0.f, 0.f};
            #pragma unroll
            for (int ks = 0; ks < 2; ks++) {
                short8 bf = *(const short8*)&Ks[nt * 16 + lo][ks * 32 + quad * 8];
                s4[nt] = __builtin_amdgcn_mfma_f32_16x16x32_bf16(qf[ks], bf, s4[nt], 0, 0, 0);
            }
        }
        // ---- scale + causal mask (diag tile only; C layout: col(key)=lo, row(q)=quad*4+r)
        bool diag = (kt == ktmax);
        int key0 = (kt - 1) * 64;
        #pragma unroll
        for (int nt = 0; nt < 4; nt++) {
            if (nt >= ntiles) break;
            #pragma unroll
            for (int r = 0; r < 4; r++) {
                float v = s4[nt][r] * 0.125f;
                if (diag) {
                    int kg = key0 + nt * 16 + lo;
                    int qq = q0 + wave * 16 + quad * 4 + r;
                    if (kg > qq) v = -1e30f;
                }
                s4[nt][r] = v;
            }
        }
        // ---- online softmax update
        float alpha[4];
        #pragma unroll
        for (int r = 0; r < 4; r++) {
            float tm = s4[0][r];
            #pragma unroll
            for (int nt = 1; nt < 4; nt++) { if (nt >= ntiles) break; tm = fmaxf(tm, s4[nt][r]); }
            #pragma unroll
            for (int msk = 1; msk <= 8; msk <<= 1) tm = fmaxf(tm, __shfl_xor(tm, msk, 64));
            float mn = fmaxf(m[r], tm);
            alpha[r] = __expf(m[r] - mn);
            float sum = 0.f;
            #pragma unroll
            for (int nt = 0; nt < 4; nt++) {
                if (nt >= ntiles) break;
                float p = __expf(s4[nt][r] - mn);
                sum += p;
                Ps[wave][quad * 4 + r][nt * 16 + lo] = f2b(p);
            }
            #pragma unroll
            for (int msk = 1; msk <= 8; msk <<= 1) sum += __shfl_xor(sum, msk, 64);
            l[r] = l[r] * alpha[r] + sum;
            m[r] = mn;
        }
        #pragma unroll
        for (int dt = 0; dt < 4; dt++)
            #pragma unroll
            for (int r = 0; r < 4; r++) o4[dt][r] *= alpha[r];
        // ensure Ps LDS writes are complete/visible before PV A-operand reads
        __syncthreads();
        // ---- O += P V
        int ksteps = (kt == 0) ? 1 : 2;
        #pragma unroll
        for (int ks = 0; ks < 2; ks++) {
            if (ks >= ksteps) break;
            short8 af = *(const short8*)&Ps[wave][lo][ks * 32 + quad * 8];
            #pragma unroll
            for (int dt = 0; dt < 4; dt++) {
                short8 bf = *(const short8*)&Vs[dt * 16 + lo][ks * 32 + quad * 8];
                o4[dt] = __builtin_amdgcn_mfma_f32_16x16x32_bf16(af, bf, o4[dt], 0, 0, 0);
            }
        }
    }
    // ---- epilogue: O /= l, write bf16 (row q = quad*4+r, col dim = dt*16+lo)
    #pragma unroll
    for (int r = 0; r < 4; r++) {
        float inv = 1.0f / l[r];
        int q = q0 + wave * 16 + quad * 4 + r;
        unsigned short* aop = ao + (long long)(b * C_ + q) * (H_ * DH_) + h * DH_ + lo;
        #pragma unroll
        for (int dt = 0; dt < 4; dt++) aop[dt * 16] = f2b(o4[dt][r] * inv);
    }
}

// ---------------------------------------------------------------- launch
extern "C" void kernel_launch(void* const* d_in, const int* in_sizes, int n_in,
                              void* d_out, int out_size, void* d_ws, size_t ws_size,
                              hipStream_t stream)
{
    const float* x     = (const float*)d_in[0];
    const float* g1    = (const float*)d_in[1];
    const float* b1    = (const float*)d_in[2];
    const float* g2    = (const float*)d_in[3];
    const float* b2    = (const float*)d_in[4];
    const float* g3    = (const float*)d_in[5];
    const float* b3    = (const float*)d_in[6];
    const float* Wqm   = (const float*)d_in[7];
    const float* Wkm   = (const float*)d_in[8];
    const float* Wvm   = (const float*)d_in[9];
    const float* lr    = (const float*)d_in[10];
    const float* mom   = (const float*)d_in[11];
    const float* fg    = (const float*)d_in[12];
    const float* Wq    = (const float*)d_in[13];
    const float* bq    = (const float*)d_in[14];
    const float* Wk    = (const float*)d_in[15];
    const float* bk    = (const float*)d_in[16];
    const float* Wv    = (const float*)d_in[17];
    const float* bv    = (const float*)d_in[18];
    const float* Wo    = (const float*)d_in[19];
    const float* bo    = (const float*)d_in[20];
    const float* pk    = (const float*)d_in[21];
    const float* pv    = (const float*)d_in[22];
    const float* Wg    = (const float*)d_in[23];
    const float* bg    = (const float*)d_in[24];
    const float* Wgate = (const float*)d_in[25];
    const float* bgate = (const float*)d_in[26];
    const float* Wup   = (const float*)d_in[27];
    const float* bup   = (const float*)d_in[28];
    const float* Wdown = (const float*)d_in[29];
    const float* bdown = (const float*)d_in[30];
    float* out = (float*)d_out;

    const long long MB = 1024LL * 1024LL;
    char* w = (char*)d_ws;
    float* M  = (float*)(w + 0 * MB);
    float* St = (float*)(w + 16 * MB);
    unsigned short* Mt = (unsigned short*)(w + 32 * MB);
    unsigned short* WqmT   = (unsigned short*)(w + 40 * MB);
    unsigned short* WkmT   = (unsigned short*)(w + 42 * MB);
    unsigned short* WvmT   = (unsigned short*)(w + 44 * MB);
    unsigned short* WqT    = (unsigned short*)(w + 46 * MB);
    unsigned short* WkT    = (unsigned short*)(w + 48 * MB);
    unsigned short* WvT    = (unsigned short*)(w + 50 * MB);
    unsigned short* WoT    = (unsigned short*)(w + 52 * MB);
    unsigned short* WgT    = (unsigned short*)(w + 54 * MB);
    unsigned short* WgateT = (unsigned short*)(w + 56 * MB);
    unsigned short* WupT   = (unsigned short*)(w + 64 * MB);
    unsigned short* WdownT = (unsigned short*)(w + 72 * MB);
    float* F0 = (float*)(w + 80 * MB);
    float* F1 = (float*)(w + 88 * MB);
    float* F2 = (float*)(w + 96 * MB);
    float* F3 = (float*)(w + 104 * MB);
    unsigned short* H0 = (unsigned short*)(w + 112 * MB);
    unsigned short* H1 = (unsigned short*)(w + 116 * MB);
    unsigned short* H2 = (unsigned short*)(w + 120 * MB);
    unsigned short* H3 = (unsigned short*)(w + 124 * MB);
    unsigned short* G0 = (unsigned short*)(w + 128 * MB);
    unsigned short* G1 = (unsigned short*)(w + 144 * MB);

    hipMemsetAsync(d_ws, 0, (size_t)(32 * MB), stream);

    transpose_f32_b16<<<dim3(32, 32, 1), 256, 0, stream>>>(Wqm, WqmT, D_, D_, 0, 0);
    transpose_f32_b16<<<dim3(32, 32, 1), 256, 0, stream>>>(Wkm, WkmT, D_, D_, 0, 0);
    transpose_f32_b16<<<dim3(32, 32, 1), 256, 0, stream>>>(Wvm, WvmT, D_, D_, 0, 0);
    transpose_f32_b16<<<dim3(32, 32, 1), 256, 0, stream>>>(Wq, WqT, D_, D_, 0, 0);
    transpose_f32_b16<<<dim3(32, 32, 1), 256, 0, stream>>>(Wk, WkT, D_, D_, 0, 0);
    transpose_f32_b16<<<dim3(32, 32, 1), 256, 0, stream>>>(Wv, WvT, D_, D_, 0, 0);
    transpose_f32_b16<<<dim3(32, 32, 1), 256, 0, stream>>>(Wo, WoT, D_, D_, 0, 0);
    transpose_f32_b16<<<dim3(32, 32, 1), 256, 0, stream>>>(Wg, WgT, D_, D_, 0, 0);
    transpose_f32_b16<<<dim3(128, 32, 1), 256, 0, stream>>>(Wgate, WgateT, D_, FF_, 0, 0);
    transpose_f32_b16<<<dim3(128, 32, 1), 256, 0, stream>>>(Wup, WupT, D_, FF_, 0, 0);
    transpose_f32_b16<<<dim3(32, 128, 1), 256, 0, stream>>>(Wdown, WdownT, FF_, D_, 0, 0);

    const long long xBS = (long long)S_ * D_;
    const long long flatD = (long long)C_ * D_;
    const dim3 gAct(16, 16, 1);
    const dim3 gMem(16, 4, 4);
    const dim3 gGrad(16, 8, 4);
    const dim3 gFF(64, 16, 1);
    const dim3 gDown(16, 4, 4);

    for (int ci = 0; ci < NC_; ci++) {
        const float* xchunk = x + (long long)ci * C_ * D_;
        float* ochunk = out + (long long)ci * C_ * D_;

        // 1) h1 = LN1(xc) -> H0
        ln_kernel<<<B_ * C_, 256, 0, stream>>>(xchunk, xBS, C_, nullptr, g1, b1, H0);
        // 2) qm -> H1 (bf16)
        gemm_mfma<<<gAct, 256, 0, stream>>>(H0, WqmT, nullptr, nullptr, nullptr, H1, D_, D_, 0, 0, 0, 0);
        // 3) km -> F1 (fp32)
        gemm_mfma<<<gAct, 256, 0, stream>>>(H0, WkmT, nullptr, nullptr, F1, nullptr, D_, D_, 0, 0, 0, 0);
        // 4) vm -> F2 (fp32)
        gemm_mfma<<<gAct, 256, 0, stream>>>(H0, WvmT, nullptr, nullptr, F2, nullptr, D_, D_, 0, 0, 0, 0);
        // 5) km normalize -> H2
        rownorm_kernel<<<B_ * C_, 256, 0, stream>>>(F1, H2);
        // 6) kmT -> H3 [z][1024][512]
        transpose_b16_b16<<<dim3(32, 16, 4), 256, 0, stream>>>(H2, H3, C_, D_, flatD, flatD);
        // 7) Mt = bf16(M^T)
        transpose_f32_b16<<<dim3(32, 32, 4), 256, 0, stream>>>(M, Mt, D_, D_, (long long)D_ * D_, (long long)D_ * D_);
        // 8) mem_ctx = qm @ M -> F0 (fp32) + H0 (bf16)
        gemm_mfma<<<gMem, 256, 0, stream>>>(H1, Mt, nullptr, nullptr, F0, H0, D_, D_, flatD, (long long)D_ * D_, 0, flatD);
        // 9) pred = km @ M -> F3
        gemm_mfma<<<gMem, 256, 0, stream>>>(H2, Mt, nullptr, nullptr, F3, nullptr, D_, D_, flatD, (long long)D_ * D_, 0, flatD);
        // 10) diffT -> H1
        subT_kernel<<<dim3(32, 16, 4), 256, 0, stream>>>(F3, F2, H1);
        // 11) grad = kmT @ diffT^T -> F2:F3 (16 MB)
        gemm_mfma<<<gGrad, 256, 0, stream>>>(H3, H1, nullptr, nullptr, F2, nullptr, C_, D_,
                                             (long long)D_ * C_, (long long)D_ * C_, 0, (long long)D_ * D_);
        // 12) momentum + forget update
        update_mem_kernel<<<(B_ * D_ * D_) / 256, 256, 0, stream>>>(M, St, F2, lr, mom, fg, (long long)B_ * D_ * D_);
        // 13) h2 = LN2(xc + mem_ctx) -> H2
        ln_kernel<<<B_ * C_, 256, 0, stream>>>(xchunk, xBS, C_, F0, g2, b2, H2);
        // 14-16) qh -> H1, kh -> H3, vh -> G0 (all bf16)
        gemm_mfma<<<gAct, 256, 0, stream>>>(H2, WqT, bq, nullptr, nullptr, H1, D_, D_, 0, 0, 0, 0);
        gemm_mfma<<<gAct, 256, 0, stream>>>(H2, WkT, bk, nullptr, nullptr, H3, D_, D_, 0, 0, 0, 0);
        gemm_mfma<<<gAct, 256, 0, stream>>>(H2, WvT, bv, nullptr, nullptr, G0, D_, D_, 0, 0, 0, 0);
        // 17) attention -> G1 (bf16)
        attn_mfma<<<dim3(C_ / 64, H_, B_), 256, 0, stream>>>(H1, H3, G0, pk, pv, G1);
        // 18) aoW = ao @ Wo + bo -> F1
        gemm_mfma<<<gAct, 256, 0, stream>>>(G1, WoT, bo, nullptr, F1, nullptr, D_, D_, 0, 0, 0, 0);
        // 19) gbuf = mem_ctx @ Wg + bg -> F2
        gemm_mfma<<<gAct, 256, 0, stream>>>(H0, WgT, bg, nullptr, F2, nullptr, D_, D_, 0, 0, 0, 0);
        // 20) o = xc + sig(gbuf)*aoW + (1-sig)*mem_ctx -> F2
        gate_combine_kernel<<<(B_ * C_ * D_) / 256, 256, 0, stream>>>(xchunk, xBS, F2, F1, F0, F2);
        // 21) h3 = LN3(o) -> H2
        ln_kernel<<<B_ * C_, 256, 0, stream>>>(F2, flatD, C_, nullptr, g3, b3, H2);
        // 22-23) gate -> G0, up -> G1 (bf16)
        gemm_mfma<<<gFF, 256, 0, stream>>>(H2, WgateT, bgate, nullptr, nullptr, G0, D_, FF_, 0, 0, 0, 0);
        gemm_mfma<<<gFF, 256, 0, stream>>>(H2, WupT, bup, nullptr, nullptr, G1, D_, FF_, 0, 0, 0, 0);
        // 24) G0 <- silu(G0)*G1
        silu_mul_b16<<<((long long)B_ * C_ * FF_ / 8) / 256, 256, 0, stream>>>(G0, G1, (long long)B_ * C_ * FF_ / 8);
        // 25) out = o + prod @ Wdown + bdown
        gemm_mfma<<<gDown, 256, 0, stream>>>(G0, WdownT, bdown, F2, ochunk, nullptr, FF_, D_,
                                             (long long)C_ * FF_, 0, flatD, xBS);
    }
}

// Round 5
// 3317.634 us; speedup vs baseline: 5.5850x; 1.2006x over previous
//
#include <hip/hip_runtime.h>
#include <hip/hip_bf16.h>
#include <math.h>

#define D_ 1024
#define C_ 512
#define H_ 16
#define DH_ 64
#define P_ 16
#define FF_ 4096
#define S_ 4096
#define B_ 4
#define NC_ 8
#define KP_ 72   // attn LDS pitch (shorts)

typedef __attribute__((ext_vector_type(8))) short short8;
typedef __attribute__((ext_vector_type(4))) float floatx4;

__device__ __forceinline__ float sigmoidf_(float x) { return 1.0f / (1.0f + expf(-x)); }
__device__ __forceinline__ unsigned short f2b(float x) {
    __hip_bfloat16 h = __float2bfloat16(x);
    return __builtin_bit_cast(unsigned short, h);
}
__device__ __forceinline__ float b2f(unsigned short u) {
    __hip_bfloat16 h = __builtin_bit_cast(__hip_bfloat16, u);
    return __bfloat162float(h);
}
// async global->LDS 16B: LDS dst = wave-uniform base + lane*16
__device__ __forceinline__ void async_cp16(const unsigned short* g, short* l) {
    __builtin_amdgcn_global_load_lds(
        (const __attribute__((address_space(1))) void*)g,
        (__attribute__((address_space(3))) void*)l, 16, 0, 0);
}

// ---------------------------------------------------------------- LayerNorm (fp32 in, bf16 out)
__global__ __launch_bounds__(256) void ln_kernel(
    const float* __restrict__ x, long long xBatchStride, int rowsPerBatch,
    const float* __restrict__ add,
    const float* __restrict__ g, const float* __restrict__ beta,
    unsigned short* __restrict__ out)
{
    __shared__ float sbuf[4];
    int row = blockIdx.x;
    int bb = row / rowsPerBatch, s = row - bb * rowsPerBatch;
    const float* xr = x + (long long)bb * xBatchStride + (long long)s * D_;
    int t = threadIdx.x;
    float v[4];
    float4 xv = *(const float4*)(xr + t * 4);
    v[0] = xv.x; v[1] = xv.y; v[2] = xv.z; v[3] = xv.w;
    if (add) {
        float4 av = *(const float4*)(add + (long long)row * D_ + t * 4);
        v[0] += av.x; v[1] += av.y; v[2] += av.z; v[3] += av.w;
    }
    float ls = v[0] + v[1] + v[2] + v[3];
    #pragma unroll
    for (int off = 32; off >= 1; off >>= 1) ls += __shfl_down(ls, off, 64);
    if ((t & 63) == 0) sbuf[t >> 6] = ls;
    __syncthreads();
    float mean = (sbuf[0] + sbuf[1] + sbuf[2] + sbuf[3]) * (1.0f / D_);
    __syncthreads();
    float lv = 0.f;
    #pragma unroll
    for (int i = 0; i < 4; i++) { float d = v[i] - mean; lv += d * d; }
    #pragma unroll
    for (int off = 32; off >= 1; off >>= 1) lv += __shfl_down(lv, off, 64);
    if ((t & 63) == 0) sbuf[t >> 6] = lv;
    __syncthreads();
    float var = (sbuf[0] + sbuf[1] + sbuf[2] + sbuf[3]) * (1.0f / D_);
    float r = rsqrtf(var + 1e-5f);
    unsigned short* orow = out + (long long)row * D_;
    #pragma unroll
    for (int i = 0; i < 4; i++) {
        int c = t * 4 + i;
        orow[c] = f2b((v[i] - mean) * r * g[c] + beta[c]);
    }
}

// ---------------------------------------------------------------- km row L2-normalize (bf16 in-place)
__global__ __launch_bounds__(256) void rownorm_b16(unsigned short* __restrict__ a)
{
    __shared__ float sbuf[4];
    int row = blockIdx.x;
    int t = threadIdx.x;
    unsigned short* ar = a + (long long)row * D_;
    ushort4 xv = *(const ushort4*)(ar + t * 4);
    float v0 = b2f(xv.x), v1 = b2f(xv.y), v2 = b2f(xv.z), v3 = b2f(xv.w);
    float ls = v0 * v0 + v1 * v1 + v2 * v2 + v3 * v3;
    #pragma unroll
    for (int off = 32; off >= 1; off >>= 1) ls += __shfl_down(ls, off, 64);
    if ((t & 63) == 0) sbuf[t >> 6] = ls;
    __syncthreads();
    float ss = sbuf[0] + sbuf[1] + sbuf[2] + sbuf[3];
    float sc = rsqrtf(ss + 1e-6f);
    ushort4 ov;
    ov.x = f2b(v0 * sc); ov.y = f2b(v1 * sc); ov.z = f2b(v2 * sc); ov.w = f2b(v3 * sc);
    *(ushort4*)(ar + t * 4) = ov;
}

// ---------------------------------------------------------------- transposes
__global__ __launch_bounds__(256) void transpose_f32_b16(
    const float* __restrict__ in, unsigned short* __restrict__ out,
    int R, int Cc, long long izs, long long ozs)
{
    __shared__ float tile[32][33];
    int z = blockIdx.z;
    const float* ib = in + (long long)z * izs;
    unsigned short* ob = out + (long long)z * ozs;
    int c0 = blockIdx.x * 32, r0 = blockIdx.y * 32;
    int tx = threadIdx.x & 31, ty = threadIdx.x >> 5;
    #pragma unroll
    for (int i = 0; i < 32; i += 8)
        tile[ty + i][tx] = ib[(long long)(r0 + ty + i) * Cc + c0 + tx];
    __syncthreads();
    #pragma unroll
    for (int i = 0; i < 32; i += 8)
        ob[(long long)(c0 + ty + i) * R + r0 + tx] = f2b(tile[tx][ty + i]);
}

__global__ __launch_bounds__(256) void transpose_b16_b16(
    const unsigned short* __restrict__ in, unsigned short* __restrict__ out,
    int R, int Cc, long long izs, long long ozs)
{
    __shared__ unsigned short tile[32][33];
    int z = blockIdx.z;
    const unsigned short* ib = in + (long long)z * izs;
    unsigned short* ob = out + (long long)z * ozs;
    int c0 = blockIdx.x * 32, r0 = blockIdx.y * 32;
    int tx = threadIdx.x & 31, ty = threadIdx.x >> 5;
    #pragma unroll
    for (int i = 0; i < 32; i += 8)
        tile[ty + i][tx] = ib[(long long)(r0 + ty + i) * Cc + c0 + tx];
    __syncthreads();
    #pragma unroll
    for (int i = 0; i < 32; i += 8)
        ob[(long long)(c0 + ty + i) * R + r0 + tx] = tile[tx][ty + i];
}

// diffT[z][d][t] = bf16(pred[z][t][d] - vm[z][t][d]), vm is bf16
__global__ __launch_bounds__(256) void subT_kernel(
    const float* __restrict__ pred, const unsigned short* __restrict__ vm,
    unsigned short* __restrict__ out)
{
    __shared__ float tile[32][33];
    int z = blockIdx.z;
    int c0 = blockIdx.x * 32, r0 = blockIdx.y * 32;
    int tx = threadIdx.x & 31, ty = threadIdx.x >> 5;
    const float* pb = pred + (long long)z * C_ * D_;
    const unsigned short* vb = vm + (long long)z * C_ * D_;
    #pragma unroll
    for (int i = 0; i < 32; i += 8) {
        long long idx = (long long)(r0 + ty + i) * D_ + c0 + tx;
        tile[ty + i][tx] = pb[idx] - b2f(vb[idx]);
    }
    __syncthreads();
    unsigned short* ob = out + (long long)z * D_ * C_;
    #pragma unroll
    for (int i = 0; i < 32; i += 8)
        ob[(long long)(c0 + ty + i) * C_ + r0 + tx] = f2b(tile[tx][ty + i]);
}

// ---------------------------------------------------------------- MFMA GEMM engine (m97-style)
// BM=128, BK=32, BN template (128 or 64). 256 thr = 4 waves.
// BN=128: wave does 64x64 (4x4 mfma). BN=64: wave does 64x32 (4x2).
// Staging via global_load_lds 16B: LDS [row][32] shorts, NO padding (required).
// subShift!=0: fused-N col-split; outputs land in contiguous sub-buffers.
template<int BN>
__global__ __launch_bounds__(256) void gemm_flat(
    const unsigned short* __restrict__ A, const unsigned short* __restrict__ BT,
    const float* __restrict__ bias, const float* __restrict__ resid,
    float* __restrict__ outF, unsigned short* __restrict__ outB,
    int K, int N, int subShift, int Mrows, int rowsPB, long long oBS)
{
    constexpr int NJ = BN / 32;
    __shared__ short As[128 * 32];
    __shared__ short Bs[BN * 32];
    int row0 = blockIdx.y * 128, col0 = blockIdx.x * BN;
    int t = threadIdx.x, wave = t >> 6, lane = t & 63;
    int quad = lane >> 4, lo = lane & 15;
    int lrow = lane >> 2, lk = (lane & 3) * 8;
    int wm = (wave & 1) * 64, wn = (wave >> 1) * (BN / 2);
    floatx4 acc[4][NJ];
    #pragma unroll
    for (int i = 0; i < 4; i++)
        #pragma unroll
        for (int j = 0; j < NJ; j++) acc[i][j] = (floatx4){0.f, 0.f, 0.f, 0.f};

    const unsigned short* gA = A + (long long)(row0 + wave * 16 + lrow) * K + lk;
    const unsigned short* gB = BT + (long long)(col0 + wave * 16 + lrow) * K + lk;
    short* lA0 = As + (wave * 16) * 32;
    short* lA1 = As + (64 + wave * 16) * 32;
    short* lB0 = Bs + (wave * 16) * 32;

    for (int k0 = 0; k0 < K; k0 += 32) {
        async_cp16(gA + k0, lA0);
        async_cp16(gA + (long long)64 * K + k0, lA1);
        async_cp16(gB + k0, lB0);
        if (BN == 128) async_cp16(gB + (long long)64 * K + k0, Bs + (64 + wave * 16) * 32);
        __syncthreads();
        short8 a[4], b[NJ];
        #pragma unroll
        for (int i = 0; i < 4; i++) a[i] = *(const short8*)&As[(wm + i * 16 + lo) * 32 + quad * 8];
        #pragma unroll
        for (int j = 0; j < NJ; j++) b[j] = *(const short8*)&Bs[(wn + j * 16 + lo) * 32 + quad * 8];
        #pragma unroll
        for (int i = 0; i < 4; i++)
            #pragma unroll
            for (int j = 0; j < NJ; j++)
                acc[i][j] = __builtin_amdgcn_mfma_f32_16x16x32_bf16(a[i], b[j], acc[i][j], 0, 0, 0);
        __syncthreads();
    }
    #pragma unroll
    for (int i = 0; i < 4; i++)
        #pragma unroll
        for (int j = 0; j < NJ; j++) {
            int col = col0 + wn + j * 16 + lo;
            float bv = bias ? bias[col] : 0.f;
            #pragma unroll
            for (int r = 0; r < 4; r++) {
                int row = row0 + wm + i * 16 + quad * 4 + r;
                float v = acc[i][j][r] + bv;
                if (resid) v += resid[(long long)row * N + col];
                long long idx;
                if (subShift)
                    idx = (((long long)(col >> subShift) * Mrows + row) << subShift)
                        + (col & ((1 << subShift) - 1));
                else
                    idx = (long long)row * N + col;
                if (outF) {
                    if (rowsPB) {
                        int bb = row / rowsPB, s = row - bb * rowsPB;
                        outF[(long long)bb * oBS + (long long)s * N + col] = v;
                    } else outF[idx] = v;
                }
                if (outB) outB[idx] = f2b(v);
            }
        }
}

// z-batched variant: A,B,out indexed by blockIdx.z. B batch = z & bmask.
// outB written only for z < zBcut.
__global__ __launch_bounds__(256) void gemm_batched(
    const unsigned short* __restrict__ A, long long Azs,
    const unsigned short* __restrict__ BT, long long Bzs, int bmask,
    float* __restrict__ outF, long long OzsF,
    unsigned short* __restrict__ outB, long long OzsB, int zBcut,
    int K, int N)
{
    __shared__ short As[128 * 32];
    __shared__ short Bs[128 * 32];
    int z = blockIdx.z;
    const unsigned short* Ab = A + (long long)z * Azs;
    const unsigned short* Bb = BT + (long long)(z & bmask) * Bzs;
    float* oF = outF + (long long)z * OzsF;
    unsigned short* oB = (outB && z < zBcut) ? outB + (long long)z * OzsB : nullptr;
    int row0 = blockIdx.y * 128, col0 = blockIdx.x * 128;
    int t = threadIdx.x, wave = t >> 6, lane = t & 63;
    int quad = lane >> 4, lo = lane & 15;
    int lrow = lane >> 2, lk = (lane & 3) * 8;
    int wm = (wave & 1) * 64, wn = (wave >> 1) * 64;
    floatx4 acc[4][4];
    #pragma unroll
    for (int i = 0; i < 4; i++)
        #pragma unroll
        for (int j = 0; j < 4; j++) acc[i][j] = (floatx4){0.f, 0.f, 0.f, 0.f};

    const unsigned short* gA = Ab + (long long)(row0 + wave * 16 + lrow) * K + lk;
    const unsigned short* gB = Bb + (long long)(col0 + wave * 16 + lrow) * K + lk;
    short* lA0 = As + (wave * 16) * 32;
    short* lA1 = As + (64 + wave * 16) * 32;
    short* lB0 = Bs + (wave * 16) * 32;
    short* lB1 = Bs + (64 + wave * 16) * 32;

    for (int k0 = 0; k0 < K; k0 += 32) {
        async_cp16(gA + k0, lA0);
        async_cp16(gA + (long long)64 * K + k0, lA1);
        async_cp16(gB + k0, lB0);
        async_cp16(gB + (long long)64 * K + k0, lB1);
        __syncthreads();
        short8 a[4], b[4];
        #pragma unroll
        for (int i = 0; i < 4; i++) a[i] = *(const short8*)&As[(wm + i * 16 + lo) * 32 + quad * 8];
        #pragma unroll
        for (int j = 0; j < 4; j++) b[j] = *(const short8*)&Bs[(wn + j * 16 + lo) * 32 + quad * 8];
        #pragma unroll
        for (int i = 0; i < 4; i++)
            #pragma unroll
            for (int j = 0; j < 4; j++)
                acc[i][j] = __builtin_amdgcn_mfma_f32_16x16x32_bf16(a[i], b[j], acc[i][j], 0, 0, 0);
        __syncthreads();
    }
    #pragma unroll
    for (int i = 0; i < 4; i++)
        #pragma unroll
        for (int j = 0; j < 4; j++) {
            int col = col0 + wn + j * 16 + lo;
            #pragma unroll
            for (int r = 0; r < 4; r++) {
                int row = row0 + wm + i * 16 + quad * 4 + r;
                long long idx = (long long)row * N + col;
                float v = acc[i][j][r];
                if (oF) oF[idx] = v;
                if (oB) oB[idx] = f2b(v);
            }
        }
}

// ---------------------------------------------------------------- elementwise
__global__ __launch_bounds__(256) void update_mem_kernel(
    float* __restrict__ M, float* __restrict__ St, const float* __restrict__ grad,
    const float* __restrict__ lr, const float* __restrict__ mom, const float* __restrict__ fg,
    long long n)
{
    long long i = (long long)blockIdx.x * 256 + threadIdx.x;
    if (i >= n) return;
    float theta = sigmoidf_(lr[0]) * (1.0f / C_);
    float eta   = sigmoidf_(mom[0]);
    float alpha = sigmoidf_(fg[0]);
    float st = eta * St[i] - theta * grad[i];
    St[i] = st;
    M[i] = (1.0f - alpha) * M[i] + st;
}

__global__ __launch_bounds__(256) void gate_combine_kernel(
    const float* __restrict__ xc, long long xBatchStride,
    const float* __restrict__ gbuf, const float* __restrict__ aoW,
    const float* __restrict__ mctx, float* __restrict__ o)
{
    long long i = (long long)blockIdx.x * 256 + threadIdx.x;
    if (i >= (long long)B_ * C_ * D_) return;
    int row = (int)(i >> 10);
    int c = (int)(i & 1023);
    int bb = row >> 9, s = row & 511;
    float g = sigmoidf_(gbuf[i]);
    float xv = xc[(long long)bb * xBatchStride + (long long)s * D_ + c];
    o[i] = xv + g * aoW[i] + (1.0f - g) * mctx[i];
}

__global__ __launch_bounds__(256) void silu_mul_b16(
    unsigned short* __restrict__ a, const unsigned short* __restrict__ b, long long n8)
{
    long long i = (long long)blockIdx.x * 256 + threadIdx.x;
    if (i >= n8) return;
    int4 av = ((const int4*)a)[i];
    int4 bv = ((const int4*)b)[i];
    unsigned short* ap = (unsigned short*)&av;
    const unsigned short* bp = (const unsigned short*)&bv;
    #pragma unroll
    for (int j = 0; j < 8; j++) {
        float x = b2f(ap[j]);
        float y = b2f(bp[j]);
        ap[j] = f2b((x / (1.0f + expf(-x))) * y);
    }
    ((int4*)a)[i] = av;
}

// ---------------------------------------------------------------- MFMA flash attention
__global__ __launch_bounds__(256) void attn_mfma(
    const unsigned short* __restrict__ qh, const unsigned short* __restrict__ kh,
    const unsigned short* __restrict__ vh,
    const float* __restrict__ pk, const float* __restrict__ pv,
    unsigned short* __restrict__ ao)
{
    __shared__ __align__(16) short Ks[64][KP_];
    __shared__ __align__(16) short Vs[64][KP_];
    __shared__ __align__(16) short Ps[4][16][KP_];
    int qb = blockIdx.x, h = blockIdx.y, b = blockIdx.z;
    int q0 = qb * 64;
    int t = threadIdx.x;
    int wave = t >> 6, lane = t & 63;
    int quad = lane >> 4, lo = lane & 15;

    short8 qf[2];
    {
        const unsigned short* qp = qh + (long long)(b * C_ + q0 + wave * 16 + lo) * (H_ * DH_)
                                   + h * DH_ + quad * 8;
        qf[0] = *(const short8*)qp;
        qf[1] = *(const short8*)(qp + 32);
    }
    floatx4 o4[4];
    #pragma unroll
    for (int dt = 0; dt < 4; dt++) o4[dt] = (floatx4){0.f, 0.f, 0.f, 0.f};
    float m[4], l[4];
    #pragma unroll
    for (int r = 0; r < 4; r++) { m[r] = -1e30f; l[r] = 0.f; }
    {
        short* pz = &Ps[wave][lo][16 + quad * 4];
        pz[0] = 0; pz[1] = 0; pz[2] = 0; pz[3] = 0;
    }

    int ktmax = qb + 1;
    for (int kt = 0; kt <= ktmax; kt++) {
        __syncthreads();
        if (kt == 0) {
            int key = t >> 4, d4 = (t & 15) * 4;
            float4 kv4 = *(const float4*)(pk + ((long long)key * H_ + h) * DH_ + d4);
            Ks[key][d4 + 0] = f2b(kv4.x); Ks[key][d4 + 1] = f2b(kv4.y);
            Ks[key][d4 + 2] = f2b(kv4.z); Ks[key][d4 + 3] = f2b(kv4.w);
            float4 vv4 = *(const float4*)(pv + ((long long)key * H_ + h) * DH_ + d4);
            Vs[d4 + 0][key] = f2b(vv4.x); Vs[d4 + 1][key] = f2b(vv4.y);
            Vs[d4 + 2][key] = f2b(vv4.z); Vs[d4 + 3][key] = f2b(vv4.w);
            int dz = t >> 2, kz = 16 + (t & 3) * 4;
            Vs[dz][kz + 0] = 0; Vs[dz][kz + 1] = 0;
            Vs[dz][kz + 2] = 0; Vs[dz][kz + 3] = 0;
        } else {
            int tok0 = (kt - 1) * 64;
            {
                int key = t >> 2, dblk = (t & 3) * 16;
                const unsigned short* kp2 = kh + (long long)(b * C_ + tok0 + key) * (H_ * DH_)
                                            + h * DH_ + dblk;
                *(short8*)&Ks[key][dblk]     = *(const short8*)kp2;
                *(short8*)&Ks[key][dblk + 8] = *(const short8*)(kp2 + 8);
            }
            {
                int kp = t & 31, dg = t >> 5;
                const unsigned short* vp0 = vh + (long long)(b * C_ + tok0 + 2 * kp) * (H_ * DH_)
                                            + h * DH_ + dg * 8;
                short8 v0 = *(const short8*)vp0;
                short8 v1 = *(const short8*)(vp0 + H_ * DH_);
                #pragma unroll
                for (int j = 0; j < 8; j++) {
                    unsigned int pk2 = ((unsigned int)(unsigned short)v1[j] << 16)
                                     | (unsigned short)v0[j];
                    *(unsigned int*)&Vs[dg * 8 + j][2 * kp] = pk2;
                }
            }
        }
        __syncthreads();

        int ntiles = (kt == 0) ? 1 : 4;
        floatx4 s4[4];
        #pragma unroll
        for (int nt = 0; nt < 4; nt++) {
            if (nt >= ntiles) break;
            s4[nt] = (floatx4){0.f, 0.f, 0.f, 0.f};
            #pragma unroll
            for (int ks = 0; ks < 2; ks++) {
                short8 bf = *(const short8*)&Ks[nt * 16 + lo][ks * 32 + quad * 8];
                s4[nt] = __builtin_amdgcn_mfma_f32_16x16x32_bf16(qf[ks], bf, s4[nt], 0, 0, 0);
            }
        }
        bool diag = (kt == ktmax);
        int key0 = (kt - 1) * 64;
        #pragma unroll
        for (int nt = 0; nt < 4; nt++) {
            if (nt >= ntiles) break;
            #pragma unroll
            for (int r = 0; r < 4; r++) {
                float v = s4[nt][r] * 0.125f;
                if (diag) {
                    int kg = key0 + nt * 16 + lo;
                    int qq = q0 + wave * 16 + quad * 4 + r;
                    if (kg > qq) v = -1e30f;
                }
                s4[nt][r] = v;
            }
        }
        float alpha[4];
        #pragma unroll
        for (int r = 0; r < 4; r++) {
            float tm = s4[0][r];
            #pragma unroll
            for (int nt = 1; nt < 4; nt++) { if (nt >= ntiles) break; tm = fmaxf(tm, s4[nt][r]); }
            #pragma unroll
            for (int msk = 1; msk <= 8; msk <<= 1) tm = fmaxf(tm, __shfl_xor(tm, msk, 64));
            float mn = fmaxf(m[r], tm);
            alpha[r] = __expf(m[r] - mn);
            float sum = 0.f;
            #pragma unroll
            for (int nt = 0; nt < 4; nt++) {
                if (nt >= ntiles) break;
                float p = __expf(s4[nt][r] - mn);
                sum += p;
                Ps[wave][quad * 4 + r][nt * 16 + lo] = f2b(p);
            }
            #pragma unroll
            for (int msk = 1; msk <= 8; msk <<= 1) sum += __shfl_xor(sum, msk, 64);
            l[r] = l[r] * alpha[r] + sum;
            m[r] = mn;
        }
        #pragma unroll
        for (int dt = 0; dt < 4; dt++)
            #pragma unroll
            for (int r = 0; r < 4; r++) o4[dt][r] *= alpha[r];
        __syncthreads();
        int ksteps = (kt == 0) ? 1 : 2;
        #pragma unroll
        for (int ks = 0; ks < 2; ks++) {
            if (ks >= ksteps) break;
            short8 af = *(const short8*)&Ps[wave][lo][ks * 32 + quad * 8];
            #pragma unroll
            for (int dt = 0; dt < 4; dt++) {
                short8 bf = *(const short8*)&Vs[dt * 16 + lo][ks * 32 + quad * 8];
                o4[dt] = __builtin_amdgcn_mfma_f32_16x16x32_bf16(af, bf, o4[dt], 0, 0, 0);
            }
        }
    }
    #pragma unroll
    for (int r = 0; r < 4; r++) {
        float inv = 1.0f / l[r];
        int q = q0 + wave * 16 + quad * 4 + r;
        unsigned short* aop = ao + (long long)(b * C_ + q) * (H_ * DH_) + h * DH_ + lo;
        #pragma unroll
        for (int dt = 0; dt < 4; dt++) aop[dt * 16] = f2b(o4[dt][r] * inv);
    }
}

// ---------------------------------------------------------------- launch
extern "C" void kernel_launch(void* const* d_in, const int* in_sizes, int n_in,
                              void* d_out, int out_size, void* d_ws, size_t ws_size,
                              hipStream_t stream)
{
    const float* x     = (const float*)d_in[0];
    const float* g1    = (const float*)d_in[1];
    const float* b1    = (const float*)d_in[2];
    const float* g2    = (const float*)d_in[3];
    const float* b2    = (const float*)d_in[4];
    const float* g3    = (const float*)d_in[5];
    const float* b3    = (const float*)d_in[6];
    const float* Wqm   = (const float*)d_in[7];
    const float* Wkm   = (const float*)d_in[8];
    const float* Wvm   = (const float*)d_in[9];
    const float* lr    = (const float*)d_in[10];
    const float* mom   = (const float*)d_in[11];
    const float* fg    = (const float*)d_in[12];
    const float* Wq    = (const float*)d_in[13];
    const float* bq    = (const float*)d_in[14];
    const float* Wk    = (const float*)d_in[15];
    const float* bk    = (const float*)d_in[16];
    const float* Wv    = (const float*)d_in[17];
    const float* bv    = (const float*)d_in[18];
    const float* Wo    = (const float*)d_in[19];
    const float* bo    = (const float*)d_in[20];
    const float* pk    = (const float*)d_in[21];
    const float* pv    = (const float*)d_in[22];
    const float* Wg    = (const float*)d_in[23];
    const float* bg    = (const float*)d_in[24];
    const float* Wgate = (const float*)d_in[25];
    const float* bgate = (const float*)d_in[26];
    const float* Wup   = (const float*)d_in[27];
    const float* bup   = (const float*)d_in[28];
    const float* Wdown = (const float*)d_in[29];
    const float* bdown = (const float*)d_in[30];
    float* out = (float*)d_out;

    const long long MB = 1024LL * 1024LL;
    char* w = (char*)d_ws;
    // ---- arena (153 MB; regions time-shared, see chunk timeline)
    float* M   = (float*)(w + 0 * MB);             // 16 MB
    float* St  = (float*)(w + 16 * MB);            // 16 MB
    unsigned short* Mt      = (unsigned short*)(w + 32 * MB);   // 8 MB
    unsigned short* WqkvmT  = (unsigned short*)(w + 40 * MB);   // 6 MB [3072][1024]
    unsigned short* WqkvhT  = (unsigned short*)(w + 46 * MB);   // 6 MB
    unsigned short* WoT     = (unsigned short*)(w + 52 * MB);   // 2 MB
    unsigned short* WgT     = (unsigned short*)(w + 54 * MB);   // 2 MB
    unsigned short* WffT    = (unsigned short*)(w + 56 * MB);   // 16 MB [8192][1024]
    unsigned short* WdownT  = (unsigned short*)(w + 72 * MB);   // 8 MB [1024][4096]
    float* bqkvh = (float*)(w + 80 * MB);                       // 12 KB
    float* bff   = (float*)(w + 80 * MB + 65536);               // 32 KB
    float* F0 = (float*)(w + 81 * MB);             // mem_ctx fp32 8 MB
    float* F3 = (float*)(w + 89 * MB);             // pred fp32 8 MB
    float* Fg = (float*)(w + 97 * MB);             // grad fp32 16 MB (t-shared)
    unsigned short* HQ = (unsigned short*)(w + 97 * MB);  // qh|kh|vh 12 MB (t-shared)
    float* F1 = (float*)(w + 113 * MB);            // aoW fp32 8 MB
    float* F2 = (float*)(w + 121 * MB);            // o fp32 8 MB
    unsigned short* G0 = (unsigned short*)(w + 89 * MB);  // gate 16 MB (t-shared w/ F3,HQ,F1)
    unsigned short* G1 = (unsigned short*)(w + 105 * MB); // up 16 MB
    unsigned short* HA  = (unsigned short*)(w + 129 * MB); // qm|km|vm 12 MB
    unsigned short* Hao = (unsigned short*)(w + 129 * MB); // attn out (reuses qm)
    unsigned short* H0  = (unsigned short*)(w + 141 * MB); // mem_ctx bf16 4 MB
    unsigned short* Hm  = (unsigned short*)(w + 145 * MB); // ln1/diffT/ln2/ln3 4 MB
    unsigned short* HkmT= (unsigned short*)(w + 149 * MB); // 4 MB

    hipMemsetAsync(d_ws, 0, (size_t)(32 * MB), stream);   // zero M, St

    // concat biases (d2d async)
    hipMemcpyAsync(bqkvh,        bq,    4096,  hipMemcpyDeviceToDevice, stream);
    hipMemcpyAsync(bqkvh + 1024, bk,    4096,  hipMemcpyDeviceToDevice, stream);
    hipMemcpyAsync(bqkvh + 2048, bv,    4096,  hipMemcpyDeviceToDevice, stream);
    hipMemcpyAsync(bff,          bgate, 16384, hipMemcpyDeviceToDevice, stream);
    hipMemcpyAsync(bff + 4096,   bup,   16384, hipMemcpyDeviceToDevice, stream);

    // weight transposes -> bf16 [N][K], fused along N
    transpose_f32_b16<<<dim3(32, 32, 1), 256, 0, stream>>>(Wqm, WqkvmT,              D_, D_, 0, 0);
    transpose_f32_b16<<<dim3(32, 32, 1), 256, 0, stream>>>(Wkm, WqkvmT + 1048576,    D_, D_, 0, 0);
    transpose_f32_b16<<<dim3(32, 32, 1), 256, 0, stream>>>(Wvm, WqkvmT + 2097152,    D_, D_, 0, 0);
    transpose_f32_b16<<<dim3(32, 32, 1), 256, 0, stream>>>(Wq,  WqkvhT,              D_, D_, 0, 0);
    transpose_f32_b16<<<dim3(32, 32, 1), 256, 0, stream>>>(Wk,  WqkvhT + 1048576,    D_, D_, 0, 0);
    transpose_f32_b16<<<dim3(32, 32, 1), 256, 0, stream>>>(Wv,  WqkvhT + 2097152,    D_, D_, 0, 0);
    transpose_f32_b16<<<dim3(32, 32, 1), 256, 0, stream>>>(Wo,  WoT,                 D_, D_, 0, 0);
    transpose_f32_b16<<<dim3(32, 32, 1), 256, 0, stream>>>(Wg,  WgT,                 D_, D_, 0, 0);
    transpose_f32_b16<<<dim3(128, 32, 1), 256, 0, stream>>>(Wgate, WffT,             D_, FF_, 0, 0);
    transpose_f32_b16<<<dim3(128, 32, 1), 256, 0, stream>>>(Wup,   WffT + 4194304,   D_, FF_, 0, 0);
    transpose_f32_b16<<<dim3(32, 128, 1), 256, 0, stream>>>(Wdown, WdownT,           FF_, D_, 0, 0);

    const long long xBS = (long long)S_ * D_;
    const long long flatD = (long long)C_ * D_;

    for (int ci = 0; ci < NC_; ci++) {
        const float* xchunk = x + (long long)ci * C_ * D_;
        float* ochunk = out + (long long)ci * C_ * D_;

        // 1) h1 = LN1(xc) -> Hm
        ln_kernel<<<B_ * C_, 256, 0, stream>>>(xchunk, xBS, C_, nullptr, g1, b1, Hm);
        // 2) fused qm|km|vm -> HA (bf16, col-split)
        gemm_flat<128><<<dim3(24, 16), 256, 0, stream>>>(Hm, WqkvmT, nullptr, nullptr,
            nullptr, HA, D_, 3072, 10, 2048, 0, 0);
        // 3) km normalize in place (HA slot 1)
        rownorm_b16<<<B_ * C_, 256, 0, stream>>>(HA + 2097152);
        // 4) kmT -> HkmT [z][1024][512]
        transpose_b16_b16<<<dim3(32, 16, 4), 256, 0, stream>>>(HA + 2097152, HkmT, C_, D_, flatD, flatD);
        // 5) Mt = bf16(M^T)
        transpose_f32_b16<<<dim3(32, 32, 4), 256, 0, stream>>>(M, Mt, D_, D_, (long long)D_ * D_, (long long)D_ * D_);
        // 6) fused mem_ctx(z=0..3) + pred(z=4..7) = [qm;km] @ Mt -> F0:F3 (+H0 bf16 z<4)
        gemm_batched<<<dim3(8, 4, 8), 256, 0, stream>>>(HA, 512LL * 1024, Mt, (long long)D_ * D_, 3,
            F0, 512LL * 1024, H0, 512LL * 1024, 4, D_, D_);
        // 7) diffT = (pred - vm)^T -> Hm [z][1024][512]
        subT_kernel<<<dim3(32, 16, 4), 256, 0, stream>>>(F3, HA + 2 * 2097152, Hm);
        // 8) grad = kmT @ diffT^T -> Fg ; momentum update
        gemm_batched<<<dim3(8, 8, 4), 256, 0, stream>>>(HkmT, (long long)D_ * C_, Hm, (long long)D_ * C_, 3,
            Fg, (long long)D_ * D_, nullptr, 0, 0, C_, D_);
        update_mem_kernel<<<(B_ * D_ * D_) / 256, 256, 0, stream>>>(M, St, Fg, lr, mom, fg, (long long)B_ * D_ * D_);
        // 9) h2 = LN2(xc + mem_ctx) -> Hm
        ln_kernel<<<B_ * C_, 256, 0, stream>>>(xchunk, xBS, C_, F0, g2, b2, Hm);
        // 10) fused qh|kh|vh -> HQ (bf16, col-split, concat bias)
        gemm_flat<128><<<dim3(24, 16), 256, 0, stream>>>(Hm, WqkvhT, bqkvh, nullptr,
            nullptr, HQ, D_, 3072, 10, 2048, 0, 0);
        // 11) attention -> Hao
        attn_mfma<<<dim3(C_ / 64, H_, B_), 256, 0, stream>>>(HQ, HQ + 2097152, HQ + 2 * 2097152, pk, pv, Hao);
        // 12) aoW = ao @ Wo + bo -> F1
        gemm_flat<64><<<dim3(16, 16), 256, 0, stream>>>(Hao, WoT, bo, nullptr,
            F1, nullptr, D_, D_, 0, 0, 0, 0);
        // 13) gbuf = mem_ctx @ Wg + bg -> F2
        gemm_flat<64><<<dim3(16, 16), 256, 0, stream>>>(H0, WgT, bg, nullptr,
            F2, nullptr, D_, D_, 0, 0, 0, 0);
        // 14) o = xc + sig(gbuf)*aoW + (1-sig)*mem_ctx -> F2
        gate_combine_kernel<<<(B_ * C_ * D_) / 256, 256, 0, stream>>>(xchunk, xBS, F2, F1, F0, F2);
        // 15) h3 = LN3(o) -> Hm
        ln_kernel<<<B_ * C_, 256, 0, stream>>>(F2, flatD, C_, nullptr, g3, b3, Hm);
        // 16) fused gate|up -> G0:G1 (bf16, col-split, concat bias)
        gemm_flat<128><<<dim3(64, 16), 256, 0, stream>>>(Hm, WffT, bff, nullptr,
            nullptr, G0, D_, 8192, 12, 2048, 0, 0);
        // 17) G0 <- silu(G0)*G1
        silu_mul_b16<<<((long long)B_ * C_ * FF_ / 8) / 256, 256, 0, stream>>>(G0, G1, (long long)B_ * C_ * FF_ / 8);
        // 18) out = o + prod @ Wdown + bdown
        gemm_flat<64><<<dim3(16, 16), 256, 0, stream>>>(G0, WdownT, bdown, F2,
            ochunk, nullptr, FF_, D_, 0, 0, C_, xBS);
    }
}